// Round 4
// baseline (545.771 us; speedup 1.0000x reference)
//
#include <hip/hip_runtime.h>

// WaveNet fused kernel for MI355X (gfx950).
// L=10 layers of pointwise convs (C=128), B=4, T=32768.
// R3: weights read DIRECT from global (bf16, L2-resident, 1MB total) instead
// of LDS-staged. Removes s_wst (LDS 66->34KB => 3-4 blocks/CU resident),
// moves ~45% of LDS-pipe traffic to the idle VMEM pipe, and removes the
// global_load_lds vmcnt-drain at barriers. Activations stay in swizzled LDS.

typedef __bf16 bf16x8 __attribute__((ext_vector_type(8)));
typedef float  f32x4  __attribute__((ext_vector_type(4)));
typedef unsigned int uint;
typedef unsigned long long u64;
typedef unsigned short u16;

#define MFMA16(a, b, c) __builtin_amdgcn_mfma_f32_16x16x32_bf16((a), (b), (c), 0, 0, 0)

__device__ __forceinline__ u16 f2bf(float f) {
    uint u = __float_as_uint(f);
    u += 0x7fffu + ((u >> 16) & 1u);   // RNE
    return (u16)(u >> 16);
}
__device__ __forceinline__ float bf2f(u16 s) {
    return __uint_as_float(((uint)s) << 16);
}
__device__ __forceinline__ u64 pack4(f32x4 v) {
    return (u64)f2bf(v[0]) | ((u64)f2bf(v[1]) << 16) |
           ((u64)f2bf(v[2]) << 32) | ((u64)f2bf(v[3]) << 48);
}

// ---------------------------------------------------------------------------
// Weight conversion: fp32 -> bf16 into d_ws, LINEAR [row][k] layout.
// Slot layout (16384 bf16 each): 0..9 Wd, 10..19 Wr, 20..29 Ws, 30 Wf1, 31 Wf2.
// ---------------------------------------------------------------------------
__global__ void convert_weights(const float* __restrict__ Wd,
                                const float* __restrict__ Wr,
                                const float* __restrict__ Ws,
                                const float* __restrict__ Wf1,
                                const float* __restrict__ Wf2,
                                u16* __restrict__ wsb) {
    int idx = blockIdx.x * 256 + threadIdx.x;
    if (idx >= 32 * 16384) return;
    int slot = idx >> 14;
    int a2   = idx & 16383;
    const float* src;
    if (slot < 10)       { src = Wd  + slot * 16384; }
    else if (slot < 20)  { src = Wr  + (slot - 10) * 16384; }
    else if (slot < 30)  { src = Ws  + (slot - 20) * 16384; }
    else if (slot == 30) { src = Wf1; }
    else                 { src = Wf2; }
    wsb[idx] = f2bf(src[a2]);
}

// ---------------------------------------------------------------------------
// Main fused kernel. Grid: 1024 blocks (4 batches * 256 tiles), 512 threads
// (8 waves, 2x4 wave grid, 64x32 wave tiles).
// LDS: s_act 32KB = Act[col 128][chan 128] bf16, byte ^= (col&7)<<4 swizzle.
// ---------------------------------------------------------------------------
__device__ __forceinline__ bf16x8 ldfrag(const unsigned char* s, int rc, int ks, int hi) {
    // 16B fragment: element (rc, k) k = 32*ks + 8*hi .. +7
    int byte = rc * 256 + (((ks << 6) + (hi << 4)) ^ ((rc & 7) << 4));
    return *(const bf16x8*)(s + byte);
}

__device__ __forceinline__ bf16x8 ldwA(const u16* __restrict__ w, int row, int ks, int hi) {
    // weight A-fragment direct from global: row-major [128][128] bf16
    return *(const bf16x8*)(w + row * 128 + ks * 32 + hi * 8);
}

__global__ __launch_bounds__(512, 2)
void wavenet_main(const float* __restrict__ x,
                  const u16* __restrict__ wsb,
                  const float* __restrict__ bd,
                  const float* __restrict__ br,
                  const float* __restrict__ bs,
                  const float* __restrict__ bf1,
                  const float* __restrict__ bf2,
                  float* __restrict__ partial) {
    __shared__ __align__(16) unsigned char s_act[32768];
    __shared__ float s_red[4][128];

    const int tid  = threadIdx.x;
    const int lane = tid & 63;
    const int wid  = tid >> 6;      // 0..7
    const int wr   = wid >> 2;      // wave row  (0..1): rows wr*64..+63
    const int wc   = wid & 3;       // wave col  (0..3): cols wc*32..+31
    const int lo   = lane & 15;
    const int hi   = lane >> 4;

    const int blk = blockIdx.x;
    const int b   = blk >> 8;               // 256 tiles per batch
    const int t0  = (blk & 255) * 128;

    // ---- stage x tile into s_act ------------------------------------------
    {
        const float* xb = x + (size_t)b * (128u * 32768u) + t0;
#pragma unroll
        for (int i = 0; i < 8; ++i) {
            int task = wid * 8 + i;         // 64 tasks: 32 chan-groups x 2 t-chunks
            int tc = task & 1;
            int cg = task >> 1;
            int t  = tc * 64 + lane;        // col in tile
            int c0 = cg * 4;
            float v0 = xb[(c0 + 0) * 32768 + t];
            float v1 = xb[(c0 + 1) * 32768 + t];
            float v2 = xb[(c0 + 2) * 32768 + t];
            float v3 = xb[(c0 + 3) * 32768 + t];
            u64 pk = (u64)f2bf(v0) | ((u64)f2bf(v1) << 16) |
                     ((u64)f2bf(v2) << 32) | ((u64)f2bf(v3) << 48);
            int byte = t * 256 + ((c0 * 2) ^ ((t & 7) << 4));
            *(u64*)(s_act + byte) = pk;
        }
    }

    // skip accumulator (fp32, persistent across layers)
    f32x4 sk[4][2];
#pragma unroll
    for (int m = 0; m < 4; ++m)
#pragma unroll
        for (int n = 0; n < 2; ++n) { f32x4 z = {0.f, 0.f, 0.f, 0.f}; sk[m][n] = z; }

    __syncthreads();    // x staged

    f32x4 h_acc[4][2];

#pragma unroll 1
    for (int l = 0; l < 10; ++l) {
        const u16* wdp = wsb + l * 16384;           // Wd_l
        const u16* wrp = wsb + (10 + l) * 16384;    // Wr_l
        const u16* wsp = wsb + (20 + l) * 16384;    // Ws_l

        // --- GEMM1: out = Wd . h + bd  (A = global, B = s_act) ------------
        f32x4 out[4][2];
#pragma unroll
        for (int m = 0; m < 4; ++m) {
            f32x4 bv = *(const f32x4*)(bd + l * 128 + wr * 64 + m * 16 + hi * 4);
#pragma unroll
            for (int n = 0; n < 2; ++n) out[m][n] = bv;
        }

#pragma unroll
        for (int ks = 0; ks < 4; ++ks) {
            bf16x8 B[2];
#pragma unroll
            for (int n = 0; n < 2; ++n) B[n] = ldfrag(s_act, wc * 32 + n * 16 + lo, ks, hi);
#pragma unroll
            for (int m = 0; m < 4; ++m) {
                bf16x8 A = ldwA(wdp, wr * 64 + m * 16 + lo, ks, hi);
#pragma unroll
                for (int n = 0; n < 2; ++n) out[m][n] = MFMA16(A, B[n], out[m][n]);
            }
        }
        __syncthreads();                        // all reads of h done

        // read h (C-init for residual GEMM) from own region, then overwrite
        // with out (bf16, bias already folded in).
        u64 hv[4][2];
#pragma unroll
        for (int m = 0; m < 4; ++m)
#pragma unroll
            for (int n = 0; n < 2; ++n) {
                int col  = wc * 32 + n * 16 + lo;
                int rowb = (wr * 64 + m * 16 + hi * 4) * 2;
                int byte = col * 256 + (rowb ^ ((col & 7) << 4));
                hv[m][n] = *(const u64*)(s_act + byte);
            }
        asm volatile("" ::: "memory");          // keep reads before writes
#pragma unroll
        for (int m = 0; m < 4; ++m)
#pragma unroll
            for (int n = 0; n < 2; ++n) {
                int col  = wc * 32 + n * 16 + lo;
                int rowb = (wr * 64 + m * 16 + hi * 4) * 2;
                int byte = col * 256 + (rowb ^ ((col & 7) << 4));
                *(u64*)(s_act + byte) = pack4(out[m][n]);
            }
#pragma unroll
        for (int m = 0; m < 4; ++m)
#pragma unroll
            for (int n = 0; n < 2; ++n) {
                f32x4 h;
                h[0] = bf2f((u16)(hv[m][n]      ));
                h[1] = bf2f((u16)(hv[m][n] >> 16));
                h[2] = bf2f((u16)(hv[m][n] >> 32));
                h[3] = bf2f((u16)(hv[m][n] >> 48));
                h_acc[m][n] = h;
            }
        __syncthreads();                        // out visible

        // --- paired GEMM2/3: sk += Ws.out ; h += Wr.out (B shared) --------
#pragma unroll
        for (int ks = 0; ks < 4; ++ks) {
            bf16x8 B[2];
#pragma unroll
            for (int n = 0; n < 2; ++n) B[n] = ldfrag(s_act, wc * 32 + n * 16 + lo, ks, hi);
#pragma unroll
            for (int m = 0; m < 4; ++m) {
                int row = wr * 64 + m * 16 + lo;
                bf16x8 Aw = ldwA(wsp, row, ks, hi);
                bf16x8 Ar = ldwA(wrp, row, ks, hi);
#pragma unroll
                for (int n = 0; n < 2; ++n) {
                    sk[m][n]    = MFMA16(Aw, B[n], sk[m][n]);
                    h_acc[m][n] = MFMA16(Ar, B[n], h_acc[m][n]);
                }
            }
        }
        // per-layer biases: skip += bs, h += br
#pragma unroll
        for (int m = 0; m < 4; ++m) {
            f32x4 bsv = *(const f32x4*)(bs + l * 128 + wr * 64 + m * 16 + hi * 4);
            f32x4 brv = *(const f32x4*)(br + l * 128 + wr * 64 + m * 16 + hi * 4);
#pragma unroll
            for (int n = 0; n < 2; ++n) { sk[m][n] += bsv; h_acc[m][n] += brv; }
        }
        __syncthreads();                        // out reads done

        if (l < 9) {
            // write h (bf16) back to act
#pragma unroll
            for (int m = 0; m < 4; ++m)
#pragma unroll
                for (int n = 0; n < 2; ++n) {
                    int col  = wc * 32 + n * 16 + lo;
                    int rowb = (wr * 64 + m * 16 + hi * 4) * 2;
                    int byte = col * 256 + (rowb ^ ((col & 7) << 4));
                    *(u64*)(s_act + byte) = pack4(h_acc[m][n]);
                }
            __syncthreads();                    // h visible
        }
    }

    // ---- final conv head --------------------------------------------------
    // act currently holds out_9 (reads all done). Write relu(skip) into act.
#pragma unroll
    for (int m = 0; m < 4; ++m)
#pragma unroll
        for (int n = 0; n < 2; ++n) {
            f32x4 v;
#pragma unroll
            for (int r = 0; r < 4; ++r) v[r] = fmaxf(sk[m][n][r], 0.f);
            int col  = wc * 32 + n * 16 + lo;
            int rowb = (wr * 64 + m * 16 + hi * 4) * 2;
            int byte = col * 256 + (rowb ^ ((col & 7) << 4));
            *(u64*)(s_act + byte) = pack4(v);
        }
    __syncthreads();

    // GEMM f1: g1 = relu(Wf1 . rs + bf1)
    const u16* wf1p = wsb + 30 * 16384;
    f32x4 g1[4][2];
#pragma unroll
    for (int m = 0; m < 4; ++m) {
        f32x4 bv = *(const f32x4*)(bf1 + wr * 64 + m * 16 + hi * 4);
#pragma unroll
        for (int n = 0; n < 2; ++n) g1[m][n] = bv;
    }
#pragma unroll
    for (int ks = 0; ks < 4; ++ks) {
        bf16x8 B[2];
#pragma unroll
        for (int n = 0; n < 2; ++n) B[n] = ldfrag(s_act, wc * 32 + n * 16 + lo, ks, hi);
#pragma unroll
        for (int m = 0; m < 4; ++m) {
            bf16x8 A = ldwA(wf1p, wr * 64 + m * 16 + lo, ks, hi);
#pragma unroll
            for (int n = 0; n < 2; ++n) g1[m][n] = MFMA16(A, B[n], g1[m][n]);
        }
    }
    __syncthreads();                            // reads done

#pragma unroll
    for (int m = 0; m < 4; ++m)
#pragma unroll
        for (int n = 0; n < 2; ++n) {
            f32x4 v;
#pragma unroll
            for (int r = 0; r < 4; ++r) v[r] = fmaxf(g1[m][n][r], 0.f);
            int col  = wc * 32 + n * 16 + lo;
            int rowb = (wr * 64 + m * 16 + hi * 4) * 2;
            int byte = col * 256 + (rowb ^ ((col & 7) << 4));
            *(u64*)(s_act + byte) = pack4(v);
        }
    __syncthreads();

    // GEMM f2: g2 = Wf2 . g1 + bf2
    const u16* wf2p = wsb + 31 * 16384;
    f32x4 g2[4][2];
#pragma unroll
    for (int m = 0; m < 4; ++m) {
        f32x4 bv = *(const f32x4*)(bf2 + wr * 64 + m * 16 + hi * 4);
#pragma unroll
        for (int n = 0; n < 2; ++n) g2[m][n] = bv;
    }
#pragma unroll
    for (int ks = 0; ks < 4; ++ks) {
        bf16x8 B[2];
#pragma unroll
        for (int n = 0; n < 2; ++n) B[n] = ldfrag(s_act, wc * 32 + n * 16 + lo, ks, hi);
#pragma unroll
        for (int m = 0; m < 4; ++m) {
            bf16x8 A = ldwA(wf2p, wr * 64 + m * 16 + lo, ks, hi);
#pragma unroll
            for (int n = 0; n < 2; ++n) g2[m][n] = MFMA16(A, B[n], g2[m][n]);
        }
    }

    // ---- column reduction (mean over T, via per-block partials) ----------
    f32x4 s[4];
#pragma unroll
    for (int m = 0; m < 4; ++m) {
        s[m] = g2[m][0] + g2[m][1];
    }
#pragma unroll
    for (int m = 0; m < 4; ++m)
#pragma unroll
        for (int r = 0; r < 4; ++r) {
            float v = s[m][r];
            v += __shfl_xor(v, 1, 16);
            v += __shfl_xor(v, 2, 16);
            v += __shfl_xor(v, 4, 16);
            v += __shfl_xor(v, 8, 16);
            s[m][r] = v;
        }
    if (lo == 0) {
#pragma unroll
        for (int m = 0; m < 4; ++m)
#pragma unroll
            for (int r = 0; r < 4; ++r)
                s_red[wc][wr * 64 + m * 16 + hi * 4 + r] = s[m][r];
    }
    __syncthreads();
    if (wc == 0) {
        int row = wr * 64 + lane;
        partial[blk * 128 + row] =
            s_red[0][row] + s_red[1][row] + s_red[2][row] + s_red[3][row];
    }
}

// ---------------------------------------------------------------------------
// Deterministic final reduce: out[b][c] = (1/T) * sum_j partial[b*256+j][c]
// ---------------------------------------------------------------------------
__global__ void reduce_partials(const float* __restrict__ partial,
                                float* __restrict__ out) {
    int b = blockIdx.x;      // 4
    int c = threadIdx.x;     // 128
    float s = 0.f;
    for (int j = 0; j < 256; ++j) s += partial[(b * 256 + j) * 128 + c];
    out[b * 128 + c] = s * (1.0f / 32768.0f);
}

extern "C" void kernel_launch(void* const* d_in, const int* in_sizes, int n_in,
                              void* d_out, int out_size, void* d_ws, size_t ws_size,
                              hipStream_t stream) {
    const float* x   = (const float*)d_in[0];
    const float* Wd  = (const float*)d_in[1];
    const float* bd  = (const float*)d_in[2];
    const float* Wr  = (const float*)d_in[3];
    const float* br  = (const float*)d_in[4];
    const float* Ws  = (const float*)d_in[5];
    const float* bs  = (const float*)d_in[6];
    const float* Wf1 = (const float*)d_in[7];
    const float* bf1 = (const float*)d_in[8];
    const float* Wf2 = (const float*)d_in[9];
    const float* bf2 = (const float*)d_in[10];

    u16*   wsb     = (u16*)d_ws;                                  // 1 MB bf16 weights
    float* partial = (float*)((char*)d_ws + 32 * 16384 * 2);      // 512 KB partials

    convert_weights<<<2048, 256, 0, stream>>>(Wd, Wr, Ws, Wf1, Wf2, wsb);
    wavenet_main<<<1024, 512, 0, stream>>>(x, wsb, bd, br, bs, bf1, bf2, partial);
    reduce_partials<<<4, 128, 0, stream>>>(partial, (float*)d_out);
}

// Round 5
// 260.646 us; speedup vs baseline: 2.0939x; 2.0939x over previous
//
#include <hip/hip_runtime.h>

// WaveNet fused kernel for MI355X (gfx950).
// L=10 layers of pointwise convs (C=128), B=4, T=32768.
// R5: back to the R1 structure (256 threads, 4 waves, 64x64 wave tiles,
// LDS-staged Wd/Ws via global_load_lds, Wr direct-global) -- it was fastest
// (262us) DESPITE 72MB of VGPR-spill traffic caused by the 128-reg cap.
// Single change: __launch_bounds__(256,1) => ~256-reg cap (empirical law:
// cap ~= 256/arg2), which fits the 64x64 tile's ~200-reg live set unspilled
// while keeping 2 blocks/CU (LDS 66KB x2 <= 160KB; 2 waves/SIMD x ~220 regs
// fits the 512-reg pool).

typedef __bf16 bf16x8 __attribute__((ext_vector_type(8)));
typedef float  f32x4  __attribute__((ext_vector_type(4)));
typedef unsigned int uint;
typedef unsigned long long u64;
typedef unsigned short u16;

#define MFMA16(a, b, c) __builtin_amdgcn_mfma_f32_16x16x32_bf16((a), (b), (c), 0, 0, 0)

__device__ __forceinline__ u16 f2bf(float f) {
    uint u = __float_as_uint(f);
    u += 0x7fffu + ((u >> 16) & 1u);   // RNE
    return (u16)(u >> 16);
}
__device__ __forceinline__ float bf2f(u16 s) {
    return __uint_as_float(((uint)s) << 16);
}
__device__ __forceinline__ u64 pack4(f32x4 v) {
    return (u64)f2bf(v[0]) | ((u64)f2bf(v[1]) << 16) |
           ((u64)f2bf(v[2]) << 32) | ((u64)f2bf(v[3]) << 48);
}

// ---------------------------------------------------------------------------
// Weight conversion: fp32 -> bf16 into d_ws.
// Slot layout (16384 bf16 each): 0..9 Wd (swizzled), 10..19 Wr (RAW, read
// direct from global), 20..29 Ws (swizzled), 30 Wf1 (swz), 31 Wf2 (swz).
// Swizzle: LDS image byte a (row r = a>>8) holds W[r][ (off ^ ((r&7)<<4))>>1 ]
// so that a LINEAR global_load_lds copy yields the bank-conflict-free layout.
// ---------------------------------------------------------------------------
__global__ void convert_weights(const float* __restrict__ Wd,
                                const float* __restrict__ Wr,
                                const float* __restrict__ Ws,
                                const float* __restrict__ Wf1,
                                const float* __restrict__ Wf2,
                                u16* __restrict__ wsb) {
    int idx = blockIdx.x * 256 + threadIdx.x;
    if (idx >= 32 * 16384) return;
    int slot = idx >> 14;
    int a2   = idx & 16383;
    int r    = a2 >> 7;     // row (output channel)
    int c    = a2 & 127;    // bf16 column index within row
    const float* src;
    bool swz = true;
    if (slot < 10)       { src = Wd  + slot * 16384; }
    else if (slot < 20)  { src = Wr  + (slot - 10) * 16384; swz = false; }
    else if (slot < 30)  { src = Ws  + (slot - 20) * 16384; }
    else if (slot == 30) { src = Wf1; }
    else                 { src = Wf2; }
    int cs = swz ? (c ^ ((r & 7) << 3)) : c;
    wsb[idx] = f2bf(src[r * 128 + cs]);
}

// ---------------------------------------------------------------------------
// Main fused kernel. Grid: 1024 blocks (4 batches * 256 tiles), 256 threads.
// LDS: s_act 32KB  = Act[col 128][chan 128] bf16, byte ^= (col&7)<<4 swizzle
//      s_wst 32KB  = staged weight matrix (pre-swizzled image, linear copy)
// ---------------------------------------------------------------------------
__device__ __forceinline__ bf16x8 ldfrag(const unsigned char* s, int rc, int ks, int hi) {
    // 16B fragment: element (rc, k) k = 32*ks + 8*hi .. +7
    int byte = rc * 256 + (((ks << 6) + (hi << 4)) ^ ((rc & 7) << 4));
    return *(const bf16x8*)(s + byte);
}

__device__ __forceinline__ void stage_w(const u16* __restrict__ gsrc,
                                        unsigned char* lds, int wid, int lane) {
    // copy 32768 bytes linearly; wave w does 1KB chunks w*8 .. w*8+7
#pragma unroll
    for (int i = 0; i < 8; ++i) {
        int chunk = wid * 8 + i;
        const u16* g = gsrc + chunk * 512 + lane * 8;   // per-lane 16B source
        __builtin_amdgcn_global_load_lds(
            (const __attribute__((address_space(1))) uint*)g,
            (__attribute__((address_space(3))) uint*)(lds + chunk * 1024),
            16, 0, 0);
    }
}

__global__ __launch_bounds__(256, 1)
void wavenet_main(const float* __restrict__ x,
                  const u16* __restrict__ wsb,
                  const float* __restrict__ bd,
                  const float* __restrict__ br,
                  const float* __restrict__ bs,
                  const float* __restrict__ bf1,
                  const float* __restrict__ bf2,
                  float* __restrict__ partial) {
    __shared__ __align__(16) unsigned char s_act[32768];
    __shared__ __align__(16) unsigned char s_wst[32768];
    __shared__ float s_red[2][128];

    const int tid  = threadIdx.x;
    const int lane = tid & 63;
    const int wid  = tid >> 6;
    const int wr   = wid >> 1;      // wave row  (0..1): rows   wr*64..+63
    const int wc   = wid & 1;       // wave col  (0..1): cols   wc*64..+63
    const int lo   = lane & 15;
    const int hi   = lane >> 4;

    const int blk = blockIdx.x;
    const int b   = blk >> 8;               // 256 tiles per batch
    const int t0  = (blk & 255) * 128;

    // ---- issue stage of Wd_0 (async), then stage x tile into s_act --------
    stage_w(wsb + 0 * 16384, s_wst, wid, lane);

    {
        const float* xb = x + (size_t)b * (128u * 32768u) + t0;
#pragma unroll
        for (int i = 0; i < 16; ++i) {
            int task = wid * 16 + i;        // 64 tasks: 32 chan-groups x 2 t-chunks
            int tc = task & 1;
            int cg = task >> 1;
            int t  = tc * 64 + lane;        // col in tile
            int c0 = cg * 4;
            float v0 = xb[(c0 + 0) * 32768 + t];
            float v1 = xb[(c0 + 1) * 32768 + t];
            float v2 = xb[(c0 + 2) * 32768 + t];
            float v3 = xb[(c0 + 3) * 32768 + t];
            u64 pk = (u64)f2bf(v0) | ((u64)f2bf(v1) << 16) |
                     ((u64)f2bf(v2) << 32) | ((u64)f2bf(v3) << 48);
            int byte = t * 256 + ((c0 * 2) ^ ((t & 7) << 4));
            *(u64*)(s_act + byte) = pk;
        }
    }

    // skip accumulator (fp32, persistent across layers)
    f32x4 sk[4][4];
#pragma unroll
    for (int m = 0; m < 4; ++m)
#pragma unroll
        for (int n = 0; n < 4; ++n) { f32x4 z = {0.f, 0.f, 0.f, 0.f}; sk[m][n] = z; }

    __syncthreads();    // x staged, Wd0 ready (barrier drains vmcnt+lgkmcnt)

    f32x4 h_acc[4][4];

#pragma unroll 1
    for (int l = 0; l < 10; ++l) {
        // --- GEMM1: out = Wd . h + bd  (A = s_wst, B = s_act) -------------
        f32x4 bdv[4];
#pragma unroll
        for (int m = 0; m < 4; ++m)
            bdv[m] = *(const f32x4*)(bd + l * 128 + wr * 64 + m * 16 + hi * 4);

        f32x4 out[4][4];
#pragma unroll
        for (int m = 0; m < 4; ++m)
#pragma unroll
            for (int n = 0; n < 4; ++n) out[m][n] = bdv[m];

#pragma unroll
        for (int ks = 0; ks < 4; ++ks) {
            bf16x8 A[4];
#pragma unroll
            for (int m = 0; m < 4; ++m) A[m] = ldfrag(s_wst, wr * 64 + m * 16 + lo, ks, hi);
#pragma unroll
            for (int n = 0; n < 4; ++n) {
                bf16x8 B = ldfrag(s_act, wc * 64 + n * 16 + lo, ks, hi);
#pragma unroll
                for (int m = 0; m < 4; ++m) out[m][n] = MFMA16(A[m], B, out[m][n]);
            }
        }
        __syncthreads();                        // all reads of h & Wd done

        // issue stage of Ws_l over Wd (reads completed at barrier)
        stage_w(wsb + (20 + l) * 16384, s_wst, wid, lane);

        // read h (C-init for residual GEMM) from own region, then overwrite
        // with out (bf16, bias already folded in).
        u64 hv[4][4];
#pragma unroll
        for (int m = 0; m < 4; ++m)
#pragma unroll
            for (int n = 0; n < 4; ++n) {
                int col  = wc * 64 + n * 16 + lo;
                int rowb = (wr * 64 + m * 16 + hi * 4) * 2;
                int byte = col * 256 + (rowb ^ ((col & 7) << 4));
                hv[m][n] = *(const u64*)(s_act + byte);
            }
        asm volatile("" ::: "memory");          // keep reads before writes
#pragma unroll
        for (int m = 0; m < 4; ++m)
#pragma unroll
            for (int n = 0; n < 4; ++n) {
                int col  = wc * 64 + n * 16 + lo;
                int rowb = (wr * 64 + m * 16 + hi * 4) * 2;
                int byte = col * 256 + (rowb ^ ((col & 7) << 4));
                *(u64*)(s_act + byte) = pack4(out[m][n]);
            }
#pragma unroll
        for (int m = 0; m < 4; ++m)
#pragma unroll
            for (int n = 0; n < 4; ++n) {
                f32x4 h;
                h[0] = bf2f((u16)(hv[m][n]      ));
                h[1] = bf2f((u16)(hv[m][n] >> 16));
                h[2] = bf2f((u16)(hv[m][n] >> 32));
                h[3] = bf2f((u16)(hv[m][n] >> 48));
                h_acc[m][n] = h;
            }
        __syncthreads();                        // out visible, Ws staged

        // --- paired GEMM2/3: sk += Ws.out ; h += Wr.out (B shared) --------
        const u16* wrp = wsb + (10 + l) * 16384;  // Wr raw (direct global A)
#pragma unroll
        for (int ks = 0; ks < 4; ++ks) {
            bf16x8 Aw[4], Ar[4];
#pragma unroll
            for (int m = 0; m < 4; ++m) {
                int row = wr * 64 + m * 16 + lo;
                Aw[m] = ldfrag(s_wst, row, ks, hi);
                Ar[m] = *(const bf16x8*)(wrp + row * 128 + ks * 32 + hi * 8);
            }
#pragma unroll
            for (int n = 0; n < 4; ++n) {
                bf16x8 B = ldfrag(s_act, wc * 64 + n * 16 + lo, ks, hi);
#pragma unroll
                for (int m = 0; m < 4; ++m) {
                    sk[m][n]    = MFMA16(Aw[m], B, sk[m][n]);
                    h_acc[m][n] = MFMA16(Ar[m], B, h_acc[m][n]);
                }
            }
        }
        // per-layer biases: skip += bs, h += br
#pragma unroll
        for (int m = 0; m < 4; ++m) {
            f32x4 bsv = *(const f32x4*)(bs + l * 128 + wr * 64 + m * 16 + hi * 4);
            f32x4 brv = *(const f32x4*)(br + l * 128 + wr * 64 + m * 16 + hi * 4);
#pragma unroll
            for (int n = 0; n < 4; ++n) { sk[m][n] += bsv; h_acc[m][n] += brv; }
        }
        __syncthreads();                        // Ws & out reads done

        if (l < 9) {
            stage_w(wsb + (l + 1) * 16384, s_wst, wid, lane);   // Wd_{l+1}
            // write h (bf16) back to act
#pragma unroll
            for (int m = 0; m < 4; ++m)
#pragma unroll
                for (int n = 0; n < 4; ++n) {
                    int col  = wc * 64 + n * 16 + lo;
                    int rowb = (wr * 64 + m * 16 + hi * 4) * 2;
                    int byte = col * 256 + (rowb ^ ((col & 7) << 4));
                    *(u64*)(s_act + byte) = pack4(h_acc[m][n]);
                }
            __syncthreads();                    // h visible, Wd ready
        }
    }

    // ---- final conv head --------------------------------------------------
    // act currently holds out_9 (reads all done). Write relu(skip) into act.
    stage_w(wsb + 30 * 16384, s_wst, wid, lane);       // Wf1
#pragma unroll
    for (int m = 0; m < 4; ++m)
#pragma unroll
        for (int n = 0; n < 4; ++n) {
            f32x4 v;
#pragma unroll
            for (int r = 0; r < 4; ++r) v[r] = fmaxf(sk[m][n][r], 0.f);
            int col  = wc * 64 + n * 16 + lo;
            int rowb = (wr * 64 + m * 16 + hi * 4) * 2;
            int byte = col * 256 + (rowb ^ ((col & 7) << 4));
            *(u64*)(s_act + byte) = pack4(v);
        }
    __syncthreads();

    // GEMM f1: g1 = relu(Wf1 . rs + bf1)
    f32x4 g1[4][4];
#pragma unroll
    for (int m = 0; m < 4; ++m) {
        f32x4 bv = *(const f32x4*)(bf1 + wr * 64 + m * 16 + hi * 4);
#pragma unroll
        for (int n = 0; n < 4; ++n) g1[m][n] = bv;
    }
#pragma unroll
    for (int ks = 0; ks < 4; ++ks) {
        bf16x8 A[4];
#pragma unroll
        for (int m = 0; m < 4; ++m) A[m] = ldfrag(s_wst, wr * 64 + m * 16 + lo, ks, hi);
#pragma unroll
        for (int n = 0; n < 4; ++n) {
            bf16x8 B = ldfrag(s_act, wc * 64 + n * 16 + lo, ks, hi);
#pragma unroll
            for (int m = 0; m < 4; ++m) g1[m][n] = MFMA16(A[m], B, g1[m][n]);
        }
    }
    __syncthreads();                            // reads done

    stage_w(wsb + 31 * 16384, s_wst, wid, lane);       // Wf2
#pragma unroll
    for (int m = 0; m < 4; ++m)
#pragma unroll
        for (int n = 0; n < 4; ++n) {
            f32x4 v;
#pragma unroll
            for (int r = 0; r < 4; ++r) v[r] = fmaxf(g1[m][n][r], 0.f);
            int col  = wc * 64 + n * 16 + lo;
            int rowb = (wr * 64 + m * 16 + hi * 4) * 2;
            int byte = col * 256 + (rowb ^ ((col & 7) << 4));
            *(u64*)(s_act + byte) = pack4(v);
        }
    __syncthreads();

    // GEMM f2: g2 = Wf2 . g1 + bf2
    f32x4 g2[4][4];
#pragma unroll
    for (int m = 0; m < 4; ++m) {
        f32x4 bv = *(const f32x4*)(bf2 + wr * 64 + m * 16 + hi * 4);
#pragma unroll
        for (int n = 0; n < 4; ++n) g2[m][n] = bv;
    }
#pragma unroll
    for (int ks = 0; ks < 4; ++ks) {
        bf16x8 A[4];
#pragma unroll
        for (int m = 0; m < 4; ++m) A[m] = ldfrag(s_wst, wr * 64 + m * 16 + lo, ks, hi);
#pragma unroll
        for (int n = 0; n < 4; ++n) {
            bf16x8 B = ldfrag(s_act, wc * 64 + n * 16 + lo, ks, hi);
#pragma unroll
            for (int m = 0; m < 4; ++m) g2[m][n] = MFMA16(A[m], B, g2[m][n]);
        }
    }

    // ---- column reduction (mean over T, via per-block partials) ----------
    f32x4 s[4];
#pragma unroll
    for (int m = 0; m < 4; ++m) {
        s[m] = g2[m][0];
#pragma unroll
        for (int n = 1; n < 4; ++n) s[m] += g2[m][n];
    }
#pragma unroll
    for (int m = 0; m < 4; ++m)
#pragma unroll
        for (int r = 0; r < 4; ++r) {
            float v = s[m][r];
            v += __shfl_xor(v, 1, 16);
            v += __shfl_xor(v, 2, 16);
            v += __shfl_xor(v, 4, 16);
            v += __shfl_xor(v, 8, 16);
            s[m][r] = v;
        }
    if (lo == 0) {
#pragma unroll
        for (int m = 0; m < 4; ++m)
#pragma unroll
            for (int r = 0; r < 4; ++r)
                s_red[wc][wr * 64 + m * 16 + hi * 4 + r] = s[m][r];
    }
    __syncthreads();
    if (wc == 0) {
        int row = wr * 64 + lane;
        partial[blk * 128 + row] = s_red[0][row] + s_red[1][row];
    }
}

// ---------------------------------------------------------------------------
// Deterministic final reduce: out[b][c] = (1/T) * sum_j partial[b*256+j][c]
// ---------------------------------------------------------------------------
__global__ void reduce_partials(const float* __restrict__ partial,
                                float* __restrict__ out) {
    int b = blockIdx.x;      // 4
    int c = threadIdx.x;     // 128
    float s = 0.f;
    for (int j = 0; j < 256; ++j) s += partial[(b * 256 + j) * 128 + c];
    out[b * 128 + c] = s * (1.0f / 32768.0f);
}

extern "C" void kernel_launch(void* const* d_in, const int* in_sizes, int n_in,
                              void* d_out, int out_size, void* d_ws, size_t ws_size,
                              hipStream_t stream) {
    const float* x   = (const float*)d_in[0];
    const float* Wd  = (const float*)d_in[1];
    const float* bd  = (const float*)d_in[2];
    const float* Wr  = (const float*)d_in[3];
    const float* br  = (const float*)d_in[4];
    const float* Ws  = (const float*)d_in[5];
    const float* bs  = (const float*)d_in[6];
    const float* Wf1 = (const float*)d_in[7];
    const float* bf1 = (const float*)d_in[8];
    const float* Wf2 = (const float*)d_in[9];
    const float* bf2 = (const float*)d_in[10];

    u16*   wsb     = (u16*)d_ws;                                  // 1 MB bf16 weights
    float* partial = (float*)((char*)d_ws + 32 * 16384 * 2);      // 512 KB partials

    convert_weights<<<2048, 256, 0, stream>>>(Wd, Wr, Ws, Wf1, Wf2, wsb);
    wavenet_main<<<1024, 256, 0, stream>>>(x, wsb, bd, br, bs, bf1, bf2, partial);
    reduce_partials<<<4, 128, 0, stream>>>(partial, (float*)d_out);
}

// Round 6
// 237.085 us; speedup vs baseline: 2.3020x; 1.0994x over previous
//
#include <hip/hip_runtime.h>

// WaveNet fused kernel for MI355X (gfx950).
// L=10 layers of pointwise convs (C=128), B=4, T=32768.
// R6 = R5 structure (256 thr, 4 waves, 64x64 wave tiles, LDS-staged Wd/Ws,
// Wr direct-global, (256,1)) + VALU reduction:
//  - all swizzled LDS addresses via 12 precomputed per-thread base offsets
//    (bW/bB/bX) + compile-time offset immediates (rc&7 == lo&7 is
//    thread-constant, so the XOR term folds into the base)
//  - pack4 via v_cvt_pk_bf16_f32 (HW RNE, 2 instrs) instead of manual RNE
//  - reduce_partials parallelized (512 blocks x 64 lanes)

typedef __bf16 bf16x8 __attribute__((ext_vector_type(8)));
typedef float  f32x4  __attribute__((ext_vector_type(4)));
typedef unsigned int uint;
typedef unsigned long long u64;
typedef unsigned short u16;

#define MFMA16(a, b, c) __builtin_amdgcn_mfma_f32_16x16x32_bf16((a), (b), (c), 0, 0, 0)

__device__ __forceinline__ u16 f2bf(float f) {
    uint u = __float_as_uint(f);
    u += 0x7fffu + ((u >> 16) & 1u);   // RNE
    return (u16)(u >> 16);
}
__device__ __forceinline__ float bf2f(u16 s) {
    return __uint_as_float(((uint)s) << 16);
}
__device__ __forceinline__ u64 pack4(f32x4 v) {
    uint a, b;
    asm("v_cvt_pk_bf16_f32 %0, %1, %2" : "=v"(a) : "v"(v[0]), "v"(v[1]));
    asm("v_cvt_pk_bf16_f32 %0, %1, %2" : "=v"(b) : "v"(v[2]), "v"(v[3]));
    return ((u64)b << 32) | (u64)a;
}

// ---------------------------------------------------------------------------
// Weight conversion: fp32 -> bf16 into d_ws.
// Slot layout (16384 bf16 each): 0..9 Wd (swizzled), 10..19 Wr (RAW, read
// direct from global), 20..29 Ws (swizzled), 30 Wf1 (swz), 31 Wf2 (swz).
// ---------------------------------------------------------------------------
__global__ void convert_weights(const float* __restrict__ Wd,
                                const float* __restrict__ Wr,
                                const float* __restrict__ Ws,
                                const float* __restrict__ Wf1,
                                const float* __restrict__ Wf2,
                                u16* __restrict__ wsb) {
    int idx = blockIdx.x * 256 + threadIdx.x;
    if (idx >= 32 * 16384) return;
    int slot = idx >> 14;
    int a2   = idx & 16383;
    int r    = a2 >> 7;     // row (output channel)
    int c    = a2 & 127;    // bf16 column index within row
    const float* src;
    bool swz = true;
    if (slot < 10)       { src = Wd  + slot * 16384; }
    else if (slot < 20)  { src = Wr  + (slot - 10) * 16384; swz = false; }
    else if (slot < 30)  { src = Ws  + (slot - 20) * 16384; }
    else if (slot == 30) { src = Wf1; }
    else                 { src = Wf2; }
    int cs = swz ? (c ^ ((r & 7) << 3)) : c;
    wsb[idx] = f2bf(src[r * 128 + cs]);
}

// ---------------------------------------------------------------------------
// Main fused kernel. Grid: 1024 blocks (4 batches * 256 tiles), 256 threads.
// LDS: s_act 32KB  = Act[col 128][chan 128] bf16, byte ^= (col&7)<<4 swizzle
//      s_wst 32KB  = staged weight matrix (pre-swizzled image, linear copy)
// ---------------------------------------------------------------------------
__device__ __forceinline__ void stage_w(const u16* __restrict__ gsrc,
                                        unsigned char* lds, int woff, int wid) {
    // copy 32768 bytes linearly; wave w does 1KB chunks w*8 .. w*8+7
#pragma unroll
    for (int i = 0; i < 8; ++i) {
        const u16* g = gsrc + woff + i * 512;
        __builtin_amdgcn_global_load_lds(
            (const __attribute__((address_space(1))) uint*)g,
            (__attribute__((address_space(3))) uint*)(lds + wid * 8192 + i * 1024),
            16, 0, 0);
    }
}

__global__ __launch_bounds__(256, 1)
void wavenet_main(const float* __restrict__ x,
                  const u16* __restrict__ wsb,
                  const float* __restrict__ bd,
                  const float* __restrict__ br,
                  const float* __restrict__ bs,
                  const float* __restrict__ bf1,
                  const float* __restrict__ bf2,
                  float* __restrict__ partial) {
    __shared__ __align__(16) unsigned char s_act[32768];
    __shared__ __align__(16) unsigned char s_wst[32768];
    __shared__ float s_red[2][128];

    const int tid  = threadIdx.x;
    const int lane = tid & 63;
    const int wid  = tid >> 6;
    const int wr   = wid >> 1;      // wave row  (0..1): rows   wr*64..+63
    const int wc   = wid & 1;       // wave col  (0..1): cols   wc*64..+63
    const int lo   = lane & 15;
    const int hi   = lane >> 4;

    // precomputed swizzled LDS base offsets (thread-constant):
    //   A-frag (weights):  s_wst + bW[ks] + m*4096
    //   B-frag (act):      s_act + bB[ks] + n*4096
    //   exchange rows:     s_act + bX[m]  + n*4096   (hv read / out,h write)
    const int xc = (lo & 7) << 4;
    int bW[4], bB[4], bX[4];
#pragma unroll
    for (int ks = 0; ks < 4; ++ks) {
        int kk = ((ks << 6) + (hi << 4)) ^ xc;
        bW[ks] = (wr * 64 + lo) * 256 + kk;
        bB[ks] = (wc * 64 + lo) * 256 + kk;
    }
#pragma unroll
    for (int m = 0; m < 4; ++m)
        bX[m] = (wc * 64 + lo) * 256 + ((wr * 128 + m * 32 + hi * 8) ^ xc);

    const int woff = wid * 4096 + lane * 8;   // stage_w per-thread src offset

    const int blk = blockIdx.x;
    const int b   = blk >> 8;               // 256 tiles per batch
    const int t0  = (blk & 255) * 128;

    // ---- issue stage of Wd_0 (async), then stage x tile into s_act --------
    stage_w(wsb + 0 * 16384, s_wst, woff, wid);

    {
        const float* xb = x + (size_t)b * (128u * 32768u) + t0;
#pragma unroll
        for (int i = 0; i < 16; ++i) {
            int task = wid * 16 + i;        // 64 tasks: 32 chan-groups x 2 t-chunks
            int tc = task & 1;
            int cg = task >> 1;
            int t  = tc * 64 + lane;        // col in tile
            int c0 = cg * 4;
            f32x4 v;
            v[0] = xb[(c0 + 0) * 32768 + t];
            v[1] = xb[(c0 + 1) * 32768 + t];
            v[2] = xb[(c0 + 2) * 32768 + t];
            v[3] = xb[(c0 + 3) * 32768 + t];
            int byte = t * 256 + ((c0 * 2) ^ ((t & 7) << 4));
            *(u64*)(s_act + byte) = pack4(v);
        }
    }

    // skip accumulator (fp32, persistent across layers)
    f32x4 sk[4][4];
#pragma unroll
    for (int m = 0; m < 4; ++m)
#pragma unroll
        for (int n = 0; n < 4; ++n) { f32x4 z = {0.f, 0.f, 0.f, 0.f}; sk[m][n] = z; }

    __syncthreads();    // x staged, Wd0 ready (barrier drains vmcnt+lgkmcnt)

    f32x4 h_acc[4][4];

#pragma unroll 1
    for (int l = 0; l < 10; ++l) {
        // --- GEMM1: out = Wd . h + bd  (A = s_wst, B = s_act) -------------
        f32x4 bdv[4];
#pragma unroll
        for (int m = 0; m < 4; ++m)
            bdv[m] = *(const f32x4*)(bd + l * 128 + wr * 64 + m * 16 + hi * 4);

        f32x4 out[4][4];
#pragma unroll
        for (int m = 0; m < 4; ++m)
#pragma unroll
            for (int n = 0; n < 4; ++n) out[m][n] = bdv[m];

#pragma unroll
        for (int ks = 0; ks < 4; ++ks) {
            bf16x8 A[4];
#pragma unroll
            for (int m = 0; m < 4; ++m) A[m] = *(const bf16x8*)(s_wst + bW[ks] + m * 4096);
#pragma unroll
            for (int n = 0; n < 4; ++n) {
                bf16x8 B = *(const bf16x8*)(s_act + bB[ks] + n * 4096);
#pragma unroll
                for (int m = 0; m < 4; ++m) out[m][n] = MFMA16(A[m], B, out[m][n]);
            }
        }
        __syncthreads();                        // all reads of h & Wd done

        // issue stage of Ws_l over Wd (reads completed at barrier)
        stage_w(wsb + (20 + l) * 16384, s_wst, woff, wid);

        // read h (C-init for residual GEMM) from own region, then overwrite
        // with out (bf16, bias already folded in).
        u64 hv[4][4];
#pragma unroll
        for (int m = 0; m < 4; ++m)
#pragma unroll
            for (int n = 0; n < 4; ++n)
                hv[m][n] = *(const u64*)(s_act + bX[m] + n * 4096);
        asm volatile("" ::: "memory");          // keep reads before writes
#pragma unroll
        for (int m = 0; m < 4; ++m)
#pragma unroll
            for (int n = 0; n < 4; ++n)
                *(u64*)(s_act + bX[m] + n * 4096) = pack4(out[m][n]);
#pragma unroll
        for (int m = 0; m < 4; ++m)
#pragma unroll
            for (int n = 0; n < 4; ++n) {
                f32x4 h;
                h[0] = bf2f((u16)(hv[m][n]      ));
                h[1] = bf2f((u16)(hv[m][n] >> 16));
                h[2] = bf2f((u16)(hv[m][n] >> 32));
                h[3] = bf2f((u16)(hv[m][n] >> 48));
                h_acc[m][n] = h;
            }
        __syncthreads();                        // out visible, Ws staged

        // --- paired GEMM2/3: sk += Ws.out ; h += Wr.out (B shared) --------
        const u16* wrp = wsb + (10 + l) * 16384;  // Wr raw (direct global A)
#pragma unroll
        for (int ks = 0; ks < 4; ++ks) {
            bf16x8 Aw[4], Ar[4];
#pragma unroll
            for (int m = 0; m < 4; ++m) {
                Aw[m] = *(const bf16x8*)(s_wst + bW[ks] + m * 4096);
                Ar[m] = *(const bf16x8*)(wrp + (wr * 64 + m * 16 + lo) * 128 + ks * 32 + hi * 8);
            }
#pragma unroll
            for (int n = 0; n < 4; ++n) {
                bf16x8 B = *(const bf16x8*)(s_act + bB[ks] + n * 4096);
#pragma unroll
                for (int m = 0; m < 4; ++m) {
                    sk[m][n]    = MFMA16(Aw[m], B, sk[m][n]);
                    h_acc[m][n] = MFMA16(Ar[m], B, h_acc[m][n]);
                }
            }
        }
        // per-layer biases: skip += bs, h += br
#pragma unroll
        for (int m = 0; m < 4; ++m) {
            f32x4 bsv = *(const f32x4*)(bs + l * 128 + wr * 64 + m * 16 + hi * 4);
            f32x4 brv = *(const f32x4*)(br + l * 128 + wr * 64 + m * 16 + hi * 4);
#pragma unroll
            for (int n = 0; n < 4; ++n) { sk[m][n] += bsv; h_acc[m][n] += brv; }
        }
        __syncthreads();                        // Ws & out reads done

        if (l < 9) {
            stage_w(wsb + (l + 1) * 16384, s_wst, woff, wid);   // Wd_{l+1}
            // write h (bf16) back to act
#pragma unroll
            for (int m = 0; m < 4; ++m)
#pragma unroll
                for (int n = 0; n < 4; ++n)
                    *(u64*)(s_act + bX[m] + n * 4096) = pack4(h_acc[m][n]);
            __syncthreads();                    // h visible, Wd ready
        }
    }

    // ---- final conv head --------------------------------------------------
    // act currently holds out_9 (reads all done). Write relu(skip) into act.
    stage_w(wsb + 30 * 16384, s_wst, woff, wid);       // Wf1
#pragma unroll
    for (int m = 0; m < 4; ++m)
#pragma unroll
        for (int n = 0; n < 4; ++n) {
            f32x4 v;
#pragma unroll
            for (int r = 0; r < 4; ++r) v[r] = fmaxf(sk[m][n][r], 0.f);
            *(u64*)(s_act + bX[m] + n * 4096) = pack4(v);
        }
    __syncthreads();

    // GEMM f1: g1 = relu(Wf1 . rs + bf1)
    f32x4 g1[4][4];
#pragma unroll
    for (int m = 0; m < 4; ++m) {
        f32x4 bv = *(const f32x4*)(bf1 + wr * 64 + m * 16 + hi * 4);
#pragma unroll
        for (int n = 0; n < 4; ++n) g1[m][n] = bv;
    }
#pragma unroll
    for (int ks = 0; ks < 4; ++ks) {
        bf16x8 A[4];
#pragma unroll
        for (int m = 0; m < 4; ++m) A[m] = *(const bf16x8*)(s_wst + bW[ks] + m * 4096);
#pragma unroll
        for (int n = 0; n < 4; ++n) {
            bf16x8 B = *(const bf16x8*)(s_act + bB[ks] + n * 4096);
#pragma unroll
            for (int m = 0; m < 4; ++m) g1[m][n] = MFMA16(A[m], B, g1[m][n]);
        }
    }
    __syncthreads();                            // reads done

    stage_w(wsb + 31 * 16384, s_wst, woff, wid);       // Wf2
#pragma unroll
    for (int m = 0; m < 4; ++m)
#pragma unroll
        for (int n = 0; n < 4; ++n) {
            f32x4 v;
#pragma unroll
            for (int r = 0; r < 4; ++r) v[r] = fmaxf(g1[m][n][r], 0.f);
            *(u64*)(s_act + bX[m] + n * 4096) = pack4(v);
        }
    __syncthreads();

    // GEMM f2: g2 = Wf2 . g1 + bf2
    f32x4 g2[4][4];
#pragma unroll
    for (int m = 0; m < 4; ++m) {
        f32x4 bv = *(const f32x4*)(bf2 + wr * 64 + m * 16 + hi * 4);
#pragma unroll
        for (int n = 0; n < 4; ++n) g2[m][n] = bv;
    }
#pragma unroll
    for (int ks = 0; ks < 4; ++ks) {
        bf16x8 A[4];
#pragma unroll
        for (int m = 0; m < 4; ++m) A[m] = *(const bf16x8*)(s_wst + bW[ks] + m * 4096);
#pragma unroll
        for (int n = 0; n < 4; ++n) {
            bf16x8 B = *(const bf16x8*)(s_act + bB[ks] + n * 4096);
#pragma unroll
            for (int m = 0; m < 4; ++m) g2[m][n] = MFMA16(A[m], B, g2[m][n]);
        }
    }

    // ---- column reduction (mean over T, via per-block partials) ----------
    f32x4 s[4];
#pragma unroll
    for (int m = 0; m < 4; ++m) {
        s[m] = g2[m][0];
#pragma unroll
        for (int n = 1; n < 4; ++n) s[m] += g2[m][n];
    }
#pragma unroll
    for (int m = 0; m < 4; ++m)
#pragma unroll
        for (int r = 0; r < 4; ++r) {
            float v = s[m][r];
            v += __shfl_xor(v, 1, 16);
            v += __shfl_xor(v, 2, 16);
            v += __shfl_xor(v, 4, 16);
            v += __shfl_xor(v, 8, 16);
            s[m][r] = v;
        }
    if (lo == 0) {
#pragma unroll
        for (int m = 0; m < 4; ++m)
#pragma unroll
            for (int r = 0; r < 4; ++r)
                s_red[wc][wr * 64 + m * 16 + hi * 4 + r] = s[m][r];
    }
    __syncthreads();
    if (wc == 0) {
        int row = wr * 64 + lane;
        partial[blk * 128 + row] = s_red[0][row] + s_red[1][row];
    }
}

// ---------------------------------------------------------------------------
// Deterministic final reduce: out[b][c] = (1/T) * sum_j partial[b*256+j][c]
// Grid: 512 blocks (b*128+c) x 64 lanes.
// ---------------------------------------------------------------------------
__global__ void reduce_partials(const float* __restrict__ partial,
                                float* __restrict__ out) {
    int bc = blockIdx.x;             // 0..511
    int b  = bc >> 7, c = bc & 127;
    int lane = threadIdx.x;          // 0..63
    float s = 0.f;
#pragma unroll
    for (int i = 0; i < 4; ++i)
        s += partial[(b * 256 + lane + 64 * i) * 128 + c];
    s += __shfl_xor(s, 32);
    s += __shfl_xor(s, 16);
    s += __shfl_xor(s, 8);
    s += __shfl_xor(s, 4);
    s += __shfl_xor(s, 2);
    s += __shfl_xor(s, 1);
    if (lane == 0) out[b * 128 + c] = s * (1.0f / 32768.0f);
}

extern "C" void kernel_launch(void* const* d_in, const int* in_sizes, int n_in,
                              void* d_out, int out_size, void* d_ws, size_t ws_size,
                              hipStream_t stream) {
    const float* x   = (const float*)d_in[0];
    const float* Wd  = (const float*)d_in[1];
    const float* bd  = (const float*)d_in[2];
    const float* Wr  = (const float*)d_in[3];
    const float* br  = (const float*)d_in[4];
    const float* Ws  = (const float*)d_in[5];
    const float* bs  = (const float*)d_in[6];
    const float* Wf1 = (const float*)d_in[7];
    const float* bf1 = (const float*)d_in[8];
    const float* Wf2 = (const float*)d_in[9];
    const float* bf2 = (const float*)d_in[10];

    u16*   wsb     = (u16*)d_ws;                                  // 1 MB bf16 weights
    float* partial = (float*)((char*)d_ws + 32 * 16384 * 2);      // 512 KB partials

    convert_weights<<<2048, 256, 0, stream>>>(Wd, Wr, Ws, Wf1, Wf2, wsb);
    wavenet_main<<<1024, 256, 0, stream>>>(x, wsb, bd, br, bs, bf1, bf2, partial);
    reduce_partials<<<512, 64, 0, stream>>>(partial, (float*)d_out);
}

// Round 8
// 209.781 us; speedup vs baseline: 2.6016x; 1.1302x over previous
//
#include <hip/hip_runtime.h>

// WaveNet fused kernel for MI355X (gfx950).
// L=10 layers of pointwise convs (C=128), B=4, T=32768.
// R8 = R6 (known-good, 237us) + Wr staged in LDS (s_wr, 32KB), one layer
// ahead via global_load_lds, so GEMM2/3 has no L2-latency loads on the
// critical path (R6 had 16 global A-frag reads per wave per layer exposed
// at 1-wave/SIMD occupancy). R7's (256,2)+overlay reverted (absmax=inf).
// LDS = 32K act + 32K wst + 32K wr + 1K red = 97KB, 1 block/CU.

typedef __bf16 bf16x8 __attribute__((ext_vector_type(8)));
typedef float  f32x4  __attribute__((ext_vector_type(4)));
typedef unsigned int uint;
typedef unsigned long long u64;
typedef unsigned short u16;

#define MFMA16(a, b, c) __builtin_amdgcn_mfma_f32_16x16x32_bf16((a), (b), (c), 0, 0, 0)

__device__ __forceinline__ u16 f2bf(float f) {
    uint u = __float_as_uint(f);
    u += 0x7fffu + ((u >> 16) & 1u);   // RNE
    return (u16)(u >> 16);
}
__device__ __forceinline__ float bf2f(u16 s) {
    return __uint_as_float(((uint)s) << 16);
}
__device__ __forceinline__ u64 pack4(f32x4 v) {
    uint a, b;
    asm("v_cvt_pk_bf16_f32 %0, %1, %2" : "=v"(a) : "v"(v[0]), "v"(v[1]));
    asm("v_cvt_pk_bf16_f32 %0, %1, %2" : "=v"(b) : "v"(v[2]), "v"(v[3]));
    return ((u64)b << 32) | (u64)a;
}

// ---------------------------------------------------------------------------
// Weight conversion: fp32 -> bf16 into d_ws, ALL slots pre-swizzled for the
// LDS image (linear global_load_lds copy yields conflict-free layout).
// Slot layout (16384 bf16): 0..9 Wd, 10..19 Wr, 20..29 Ws, 30 Wf1, 31 Wf2.
// ---------------------------------------------------------------------------
__global__ void convert_weights(const float* __restrict__ Wd,
                                const float* __restrict__ Wr,
                                const float* __restrict__ Ws,
                                const float* __restrict__ Wf1,
                                const float* __restrict__ Wf2,
                                u16* __restrict__ wsb) {
    int idx = blockIdx.x * 256 + threadIdx.x;
    if (idx >= 32 * 16384) return;
    int slot = idx >> 14;
    int a2   = idx & 16383;
    int r    = a2 >> 7;     // row (output channel)
    int c    = a2 & 127;    // bf16 column index within row
    const float* src;
    if (slot < 10)       { src = Wd  + slot * 16384; }
    else if (slot < 20)  { src = Wr  + (slot - 10) * 16384; }
    else if (slot < 30)  { src = Ws  + (slot - 20) * 16384; }
    else if (slot == 30) { src = Wf1; }
    else                 { src = Wf2; }
    int cs = c ^ ((r & 7) << 3);
    wsb[idx] = f2bf(src[r * 128 + cs]);
}

// ---------------------------------------------------------------------------
// Main fused kernel. Grid: 1024 blocks (4 batches * 256 tiles), 256 threads.
// LDS: s_act 32KB = Act[col 128][chan 128] bf16, byte ^= (col&7)<<4 swizzle
//      s_wst 32KB = staged Wd/Ws/Wf (pre-swizzled image, linear copy)
//      s_wr  32KB = staged Wr (one layer ahead)
// ---------------------------------------------------------------------------
__device__ __forceinline__ void stage_w(const u16* __restrict__ gsrc,
                                        unsigned char* lds, int woff, int wid) {
    // copy 32768 bytes linearly; wave w does 1KB chunks w*8 .. w*8+7
#pragma unroll
    for (int i = 0; i < 8; ++i) {
        const u16* g = gsrc + woff + i * 512;
        __builtin_amdgcn_global_load_lds(
            (const __attribute__((address_space(1))) uint*)g,
            (__attribute__((address_space(3))) uint*)(lds + wid * 8192 + i * 1024),
            16, 0, 0);
    }
}

__global__ __launch_bounds__(256, 1)
void wavenet_main(const float* __restrict__ x,
                  const u16* __restrict__ wsb,
                  const float* __restrict__ bd,
                  const float* __restrict__ br,
                  const float* __restrict__ bs,
                  const float* __restrict__ bf1,
                  const float* __restrict__ bf2,
                  float* __restrict__ partial) {
    __shared__ __align__(16) unsigned char s_act[32768];
    __shared__ __align__(16) unsigned char s_wst[32768];
    __shared__ __align__(16) unsigned char s_wr[32768];
    __shared__ float s_red[2][128];

    const int tid  = threadIdx.x;
    const int lane = tid & 63;
    const int wid  = tid >> 6;
    const int wr   = wid >> 1;      // wave row  (0..1): rows   wr*64..+63
    const int wc   = wid & 1;       // wave col  (0..1): cols   wc*64..+63
    const int lo   = lane & 15;
    const int hi   = lane >> 4;

    // precomputed swizzled LDS base offsets (thread-constant):
    //   A-frag (weights):  s_wst/s_wr + bW[ks] + m*4096
    //   B-frag (act):      s_act + bB[ks] + n*4096
    //   exchange rows:     s_act + bX[m]  + n*4096   (hv read / out,h write)
    const int xc = (lo & 7) << 4;
    int bW[4], bB[4], bX[4];
#pragma unroll
    for (int ks = 0; ks < 4; ++ks) {
        int kk = ((ks << 6) + (hi << 4)) ^ xc;
        bW[ks] = (wr * 64 + lo) * 256 + kk;
        bB[ks] = (wc * 64 + lo) * 256 + kk;
    }
#pragma unroll
    for (int m = 0; m < 4; ++m)
        bX[m] = (wc * 64 + lo) * 256 + ((wr * 128 + m * 32 + hi * 8) ^ xc);

    const int woff = wid * 4096 + lane * 8;   // stage_w per-thread src offset

    const int blk = blockIdx.x;
    const int b   = blk >> 8;               // 256 tiles per batch
    const int t0  = (blk & 255) * 128;

    // ---- issue stage of Wd_0 + Wr_0 (async), then stage x tile into s_act --
    stage_w(wsb + 0 * 16384, s_wst, woff, wid);
    stage_w(wsb + 10 * 16384, s_wr, woff, wid);

    {
        const float* xb = x + (size_t)b * (128u * 32768u) + t0;
#pragma unroll
        for (int i = 0; i < 16; ++i) {
            int task = wid * 16 + i;        // 64 tasks: 32 chan-groups x 2 t-chunks
            int tc = task & 1;
            int cg = task >> 1;
            int t  = tc * 64 + lane;        // col in tile
            int c0 = cg * 4;
            f32x4 v;
            v[0] = xb[(c0 + 0) * 32768 + t];
            v[1] = xb[(c0 + 1) * 32768 + t];
            v[2] = xb[(c0 + 2) * 32768 + t];
            v[3] = xb[(c0 + 3) * 32768 + t];
            int byte = t * 256 + ((c0 * 2) ^ ((t & 7) << 4));
            *(u64*)(s_act + byte) = pack4(v);
        }
    }

    // skip accumulator (fp32, persistent across layers)
    f32x4 sk[4][4];
#pragma unroll
    for (int m = 0; m < 4; ++m)
#pragma unroll
        for (int n = 0; n < 4; ++n) { f32x4 z = {0.f, 0.f, 0.f, 0.f}; sk[m][n] = z; }

    __syncthreads();    // x staged, Wd0+Wr0 ready (barrier drains vmcnt+lgkmcnt)

    f32x4 h_acc[4][4];

#pragma unroll 1
    for (int l = 0; l < 10; ++l) {
        // --- GEMM1: out = Wd . h + bd  (A = s_wst, B = s_act) -------------
        f32x4 bdv[4];
#pragma unroll
        for (int m = 0; m < 4; ++m)
            bdv[m] = *(const f32x4*)(bd + l * 128 + wr * 64 + m * 16 + hi * 4);

        f32x4 out[4][4];
#pragma unroll
        for (int m = 0; m < 4; ++m)
#pragma unroll
            for (int n = 0; n < 4; ++n) out[m][n] = bdv[m];

#pragma unroll
        for (int ks = 0; ks < 4; ++ks) {
            bf16x8 A[4];
#pragma unroll
            for (int m = 0; m < 4; ++m) A[m] = *(const bf16x8*)(s_wst + bW[ks] + m * 4096);
#pragma unroll
            for (int n = 0; n < 4; ++n) {
                bf16x8 B = *(const bf16x8*)(s_act + bB[ks] + n * 4096);
#pragma unroll
                for (int m = 0; m < 4; ++m) out[m][n] = MFMA16(A[m], B, out[m][n]);
            }
        }
        __syncthreads();                        // all reads of h & Wd done

        // issue stage of Ws_l over Wd (reads completed at barrier)
        stage_w(wsb + (20 + l) * 16384, s_wst, woff, wid);

        // read h (C-init for residual GEMM) from own region, then overwrite
        // with out (bf16, bias already folded in).
        u64 hv[4][4];
#pragma unroll
        for (int m = 0; m < 4; ++m)
#pragma unroll
            for (int n = 0; n < 4; ++n)
                hv[m][n] = *(const u64*)(s_act + bX[m] + n * 4096);
        asm volatile("" ::: "memory");          // keep reads before writes
#pragma unroll
        for (int m = 0; m < 4; ++m)
#pragma unroll
            for (int n = 0; n < 4; ++n)
                *(u64*)(s_act + bX[m] + n * 4096) = pack4(out[m][n]);
#pragma unroll
        for (int m = 0; m < 4; ++m)
#pragma unroll
            for (int n = 0; n < 4; ++n) {
                f32x4 h;
                h[0] = bf2f((u16)(hv[m][n]      ));
                h[1] = bf2f((u16)(hv[m][n] >> 16));
                h[2] = bf2f((u16)(hv[m][n] >> 32));
                h[3] = bf2f((u16)(hv[m][n] >> 48));
                h_acc[m][n] = h;
            }
        __syncthreads();                        // out visible, Ws staged

        // --- paired GEMM2/3: sk += Ws.out ; h += Wr.out (B shared) --------
        // Aw from s_wst, Ar from s_wr (both LDS, conflict-free swizzle)
#pragma unroll
        for (int ks = 0; ks < 4; ++ks) {
            bf16x8 Aw[4], Ar[4];
#pragma unroll
            for (int m = 0; m < 4; ++m) {
                Aw[m] = *(const bf16x8*)(s_wst + bW[ks] + m * 4096);
                Ar[m] = *(const bf16x8*)(s_wr  + bW[ks] + m * 4096);
            }
#pragma unroll
            for (int n = 0; n < 4; ++n) {
                bf16x8 B = *(const bf16x8*)(s_act + bB[ks] + n * 4096);
#pragma unroll
                for (int m = 0; m < 4; ++m) {
                    sk[m][n]    = MFMA16(Aw[m], B, sk[m][n]);
                    h_acc[m][n] = MFMA16(Ar[m], B, h_acc[m][n]);
                }
            }
        }
        // per-layer biases: skip += bs, h += br
#pragma unroll
        for (int m = 0; m < 4; ++m) {
            f32x4 bsv = *(const f32x4*)(bs + l * 128 + wr * 64 + m * 16 + hi * 4);
            f32x4 brv = *(const f32x4*)(br + l * 128 + wr * 64 + m * 16 + hi * 4);
#pragma unroll
            for (int n = 0; n < 4; ++n) { sk[m][n] += bsv; h_acc[m][n] += brv; }
        }
        __syncthreads();                        // Ws, Wr & out reads done

        if (l < 9) {
            stage_w(wsb + (l + 1) * 16384, s_wst, woff, wid);   // Wd_{l+1}
            stage_w(wsb + (11 + l) * 16384, s_wr, woff, wid);   // Wr_{l+1}
            // write h (bf16) back to act
#pragma unroll
            for (int m = 0; m < 4; ++m)
#pragma unroll
                for (int n = 0; n < 4; ++n)
                    *(u64*)(s_act + bX[m] + n * 4096) = pack4(h_acc[m][n]);
            __syncthreads();                    // h visible, Wd+Wr ready
        }
    }

    // ---- final conv head --------------------------------------------------
    // act currently holds out_9 (reads all done). Write relu(skip) into act.
    stage_w(wsb + 30 * 16384, s_wst, woff, wid);       // Wf1
#pragma unroll
    for (int m = 0; m < 4; ++m)
#pragma unroll
        for (int n = 0; n < 4; ++n) {
            f32x4 v;
#pragma unroll
            for (int r = 0; r < 4; ++r) v[r] = fmaxf(sk[m][n][r], 0.f);
            *(u64*)(s_act + bX[m] + n * 4096) = pack4(v);
        }
    __syncthreads();

    // GEMM f1: g1 = relu(Wf1 . rs + bf1)
    f32x4 g1[4][4];
#pragma unroll
    for (int m = 0; m < 4; ++m) {
        f32x4 bv = *(const f32x4*)(bf1 + wr * 64 + m * 16 + hi * 4);
#pragma unroll
        for (int n = 0; n < 4; ++n) g1[m][n] = bv;
    }
#pragma unroll
    for (int ks = 0; ks < 4; ++ks) {
        bf16x8 A[4];
#pragma unroll
        for (int m = 0; m < 4; ++m) A[m] = *(const bf16x8*)(s_wst + bW[ks] + m * 4096);
#pragma unroll
        for (int n = 0; n < 4; ++n) {
            bf16x8 B = *(const bf16x8*)(s_act + bB[ks] + n * 4096);
#pragma unroll
            for (int m = 0; m < 4; ++m) g1[m][n] = MFMA16(A[m], B, g1[m][n]);
        }
    }
    __syncthreads();                            // reads done

    stage_w(wsb + 31 * 16384, s_wst, woff, wid);       // Wf2
#pragma unroll
    for (int m = 0; m < 4; ++m)
#pragma unroll
        for (int n = 0; n < 4; ++n) {
            f32x4 v;
#pragma unroll
            for (int r = 0; r < 4; ++r) v[r] = fmaxf(g1[m][n][r], 0.f);
            *(u64*)(s_act + bX[m] + n * 4096) = pack4(v);
        }
    __syncthreads();

    // GEMM f2: g2 = Wf2 . g1 + bf2
    f32x4 g2[4][4];
#pragma unroll
    for (int m = 0; m < 4; ++m) {
        f32x4 bv = *(const f32x4*)(bf2 + wr * 64 + m * 16 + hi * 4);
#pragma unroll
        for (int n = 0; n < 4; ++n) g2[m][n] = bv;
    }
#pragma unroll
    for (int ks = 0; ks < 4; ++ks) {
        bf16x8 A[4];
#pragma unroll
        for (int m = 0; m < 4; ++m) A[m] = *(const bf16x8*)(s_wst + bW[ks] + m * 4096);
#pragma unroll
        for (int n = 0; n < 4; ++n) {
            bf16x8 B = *(const bf16x8*)(s_act + bB[ks] + n * 4096);
#pragma unroll
            for (int m = 0; m < 4; ++m) g2[m][n] = MFMA16(A[m], B, g2[m][n]);
        }
    }

    // ---- column reduction (mean over T, via per-block partials) ----------
    f32x4 s[4];
#pragma unroll
    for (int m = 0; m < 4; ++m) {
        s[m] = g2[m][0];
#pragma unroll
        for (int n = 1; n < 4; ++n) s[m] += g2[m][n];
    }
#pragma unroll
    for (int m = 0; m < 4; ++m)
#pragma unroll
        for (int r = 0; r < 4; ++r) {
            float v = s[m][r];
            v += __shfl_xor(v, 1, 16);
            v += __shfl_xor(v, 2, 16);
            v += __shfl_xor(v, 4, 16);
            v += __shfl_xor(v, 8, 16);
            s[m][r] = v;
        }
    if (lo == 0) {
#pragma unroll
        for (int m = 0; m < 4; ++m)
#pragma unroll
            for (int r = 0; r < 4; ++r)
                s_red[wc][wr * 64 + m * 16 + hi * 4 + r] = s[m][r];
    }
    __syncthreads();
    if (wc == 0) {
        int row = wr * 64 + lane;
        partial[blk * 128 + row] = s_red[0][row] + s_red[1][row];
    }
}

// ---------------------------------------------------------------------------
// Deterministic final reduce: out[b][c] = (1/T) * sum_j partial[b*256+j][c]
// Grid: 512 blocks (b*128+c) x 64 lanes.
// ---------------------------------------------------------------------------
__global__ void reduce_partials(const float* __restrict__ partial,
                                float* __restrict__ out) {
    int bc = blockIdx.x;             // 0..511
    int b  = bc >> 7, c = bc & 127;
    int lane = threadIdx.x;          // 0..63
    float s = 0.f;
#pragma unroll
    for (int i = 0; i < 4; ++i)
        s += partial[(b * 256 + lane + 64 * i) * 128 + c];
    s += __shfl_xor(s, 32);
    s += __shfl_xor(s, 16);
    s += __shfl_xor(s, 8);
    s += __shfl_xor(s, 4);
    s += __shfl_xor(s, 2);
    s += __shfl_xor(s, 1);
    if (lane == 0) out[b * 128 + c] = s * (1.0f / 32768.0f);
}

extern "C" void kernel_launch(void* const* d_in, const int* in_sizes, int n_in,
                              void* d_out, int out_size, void* d_ws, size_t ws_size,
                              hipStream_t stream) {
    const float* x   = (const float*)d_in[0];
    const float* Wd  = (const float*)d_in[1];
    const float* bd  = (const float*)d_in[2];
    const float* Wr  = (const float*)d_in[3];
    const float* br  = (const float*)d_in[4];
    const float* Ws  = (const float*)d_in[5];
    const float* bs  = (const float*)d_in[6];
    const float* Wf1 = (const float*)d_in[7];
    const float* bf1 = (const float*)d_in[8];
    const float* Wf2 = (const float*)d_in[9];
    const float* bf2 = (const float*)d_in[10];

    u16*   wsb     = (u16*)d_ws;                                  // 1 MB bf16 weights
    float* partial = (float*)((char*)d_ws + 32 * 16384 * 2);      // 512 KB partials

    convert_weights<<<2048, 256, 0, stream>>>(Wd, Wr, Ws, Wf1, Wf2, wsb);
    wavenet_main<<<1024, 256, 0, stream>>>(x, wsb, bd, br, bs, bf1, bf2, partial);
    reduce_partials<<<512, 64, 0, stream>>>(partial, (float*)d_out);
}

// Round 10
// 188.448 us; speedup vs baseline: 2.8961x; 1.1132x over previous
//
#include <hip/hip_runtime.h>

// WaveNet fused kernel for MI355X (gfx950).
// L=10 layers of pointwise convs (C=128), B=4, T=32768.
// R10 = R9's 8-wave structure with LDS cut to EXACTLY 128 KiB (131072 B):
// R9 asked for 133120 B of static LDS; per-WG limit is 128 KiB, the launch
// was silently rejected (<<<>>> errors unchecked) and reduce_partials summed
// uninitialized d_ws garbage -> absmax=inf. Fix: drop s_red entirely (each
// wave writes its reduced column-sums straight to global partial[blk][wc][.]),
// LDS = act 64K + wst 32K + wr 32K = 131072. __launch_bounds__(512) single
// arg (launchability cap only, <=256 regs/wave).

typedef __bf16 bf16x8 __attribute__((ext_vector_type(8)));
typedef float  f32x4  __attribute__((ext_vector_type(4)));
typedef unsigned int uint;
typedef unsigned long long u64;
typedef unsigned short u16;

#define MFMA16(a, b, c) __builtin_amdgcn_mfma_f32_16x16x32_bf16((a), (b), (c), 0, 0, 0)

__device__ __forceinline__ u16 f2bf(float f) {
    uint u = __float_as_uint(f);
    u += 0x7fffu + ((u >> 16) & 1u);   // RNE
    return (u16)(u >> 16);
}
__device__ __forceinline__ float bf2f(u16 s) {
    return __uint_as_float(((uint)s) << 16);
}
__device__ __forceinline__ u64 pack4(f32x4 v) {
    uint a, b;
    asm("v_cvt_pk_bf16_f32 %0, %1, %2" : "=v"(a) : "v"(v[0]), "v"(v[1]));
    asm("v_cvt_pk_bf16_f32 %0, %1, %2" : "=v"(b) : "v"(v[2]), "v"(v[3]));
    return ((u64)b << 32) | (u64)a;
}

// ---------------------------------------------------------------------------
// Weight conversion: fp32 -> bf16 into d_ws, ALL slots pre-swizzled for the
// LDS image (linear global_load_lds copy yields conflict-free layout).
// Slot layout (16384 bf16): 0..9 Wd, 10..19 Wr, 20..29 Ws, 30 Wf1, 31 Wf2.
// ---------------------------------------------------------------------------
__global__ void convert_weights(const float* __restrict__ Wd,
                                const float* __restrict__ Wr,
                                const float* __restrict__ Ws,
                                const float* __restrict__ Wf1,
                                const float* __restrict__ Wf2,
                                u16* __restrict__ wsb) {
    int idx = blockIdx.x * 256 + threadIdx.x;
    if (idx >= 32 * 16384) return;
    int slot = idx >> 14;
    int a2   = idx & 16383;
    int r    = a2 >> 7;     // row (output channel)
    int c    = a2 & 127;    // bf16 column index within row
    const float* src;
    if (slot < 10)       { src = Wd  + slot * 16384; }
    else if (slot < 20)  { src = Wr  + (slot - 10) * 16384; }
    else if (slot < 30)  { src = Ws  + (slot - 20) * 16384; }
    else if (slot == 30) { src = Wf1; }
    else                 { src = Wf2; }
    int cs = c ^ ((r & 7) << 3);
    wsb[idx] = f2bf(src[r * 128 + cs]);
}

// ---------------------------------------------------------------------------
// Main fused kernel. Grid: 512 blocks (4 batches * 128 tiles), 512 threads
// (8 waves = 2 row-groups x 4 col-groups, each wave a 64x64 tile).
// LDS: s_act 64KB = Act[col 256][chan 128] bf16, byte ^= (col&7)<<4 swizzle
//      s_wst 32KB = staged Wd/Ws/Wf (pre-swizzled image, linear copy)
//      s_wr  32KB = staged Wr          -- total exactly 131072 B
// ---------------------------------------------------------------------------
__device__ __forceinline__ void stage_w(const u16* __restrict__ gsrc,
                                        unsigned char* lds, int woff, int wid) {
    // copy 32768 bytes linearly; 8 waves x 4 chunks of 1KB
#pragma unroll
    for (int i = 0; i < 4; ++i) {
        const u16* g = gsrc + woff + i * 512;
        __builtin_amdgcn_global_load_lds(
            (const __attribute__((address_space(1))) uint*)g,
            (__attribute__((address_space(3))) uint*)(lds + wid * 4096 + i * 1024),
            16, 0, 0);
    }
}

__global__ __launch_bounds__(512)
void wavenet_main(const float* __restrict__ x,
                  const u16* __restrict__ wsb,
                  const float* __restrict__ bd,
                  const float* __restrict__ br,
                  const float* __restrict__ bs,
                  const float* __restrict__ bf1,
                  const float* __restrict__ bf2,
                  float* __restrict__ partial) {
    __shared__ __align__(16) unsigned char s_act[65536];
    __shared__ __align__(16) unsigned char s_wst[32768];
    __shared__ __align__(16) unsigned char s_wr[32768];

    const int tid  = threadIdx.x;
    const int lane = tid & 63;
    const int wid  = tid >> 6;      // 0..7
    const int wr   = wid >> 2;      // wave row (0..1): rows wr*64..+63
    const int wc   = wid & 3;       // wave col (0..3): cols wc*64..+63
    const int lo   = lane & 15;
    const int hi   = lane >> 4;

    // precomputed swizzled LDS base offsets (thread-constant):
    //   A-frag (weights):  s_wst/s_wr + bW[ks] + m*4096
    //   B-frag (act):      s_act + bB[ks] + n*4096
    //   exchange rows:     s_act + bX[m]  + n*4096   (hv read / out,h write)
    const int xc = (lo & 7) << 4;
    int bW[4], bB[4], bX[4];
#pragma unroll
    for (int ks = 0; ks < 4; ++ks) {
        int kk = ((ks << 6) + (hi << 4)) ^ xc;
        bW[ks] = (wr * 64 + lo) * 256 + kk;
        bB[ks] = (wc * 64 + lo) * 256 + kk;
    }
#pragma unroll
    for (int m = 0; m < 4; ++m)
        bX[m] = (wc * 64 + lo) * 256 + ((wr * 128 + m * 32 + hi * 8) ^ xc);

    const int woff = wid * 2048 + lane * 8;   // stage_w per-thread src offset

    const int blk = blockIdx.x;
    const int b   = blk >> 7;               // 128 tiles per batch
    const int t0  = (blk & 127) * 256;

    // ---- issue stage of Wd_0 + Wr_0 (async), then stage x tile into s_act --
    stage_w(wsb + 0 * 16384, s_wst, woff, wid);
    stage_w(wsb + 10 * 16384, s_wr, woff, wid);

    {
        const float* xb = x + (size_t)b * (128u * 32768u) + t0;
#pragma unroll
        for (int i = 0; i < 16; ++i) {
            int task = wid * 16 + i;        // 128 tasks: 32 chan-groups x 4 t-chunks
            int tc = task & 3;
            int cg = task >> 2;
            int t  = tc * 64 + lane;        // col in tile (0..255)
            int c0 = cg * 4;
            f32x4 v;
            v[0] = xb[(c0 + 0) * 32768 + t];
            v[1] = xb[(c0 + 1) * 32768 + t];
            v[2] = xb[(c0 + 2) * 32768 + t];
            v[3] = xb[(c0 + 3) * 32768 + t];
            int byte = t * 256 + ((c0 * 2) ^ ((t & 7) << 4));
            *(u64*)(s_act + byte) = pack4(v);
        }
    }

    // skip accumulator (fp32, persistent across layers)
    f32x4 sk[4][4];
#pragma unroll
    for (int m = 0; m < 4; ++m)
#pragma unroll
        for (int n = 0; n < 4; ++n) { f32x4 z = {0.f, 0.f, 0.f, 0.f}; sk[m][n] = z; }

    __syncthreads();    // x staged, Wd0+Wr0 ready (barrier drains vmcnt+lgkmcnt)

    f32x4 h_acc[4][4];

#pragma unroll 1
    for (int l = 0; l < 10; ++l) {
        // --- GEMM1: out = Wd . h + bd  (A = s_wst, B = s_act) -------------
        f32x4 bdv[4];
#pragma unroll
        for (int m = 0; m < 4; ++m)
            bdv[m] = *(const f32x4*)(bd + l * 128 + wr * 64 + m * 16 + hi * 4);

        f32x4 out[4][4];
#pragma unroll
        for (int m = 0; m < 4; ++m)
#pragma unroll
            for (int n = 0; n < 4; ++n) out[m][n] = bdv[m];

#pragma unroll
        for (int ks = 0; ks < 4; ++ks) {
            bf16x8 A[4];
#pragma unroll
            for (int m = 0; m < 4; ++m) A[m] = *(const bf16x8*)(s_wst + bW[ks] + m * 4096);
#pragma unroll
            for (int n = 0; n < 4; ++n) {
                bf16x8 B = *(const bf16x8*)(s_act + bB[ks] + n * 4096);
#pragma unroll
                for (int m = 0; m < 4; ++m) out[m][n] = MFMA16(A[m], B, out[m][n]);
            }
        }
        __syncthreads();                        // all reads of h & Wd done

        // issue stage of Ws_l over Wd (reads completed at barrier)
        stage_w(wsb + (20 + l) * 16384, s_wst, woff, wid);

        // read h (C-init for residual GEMM) from own region, then overwrite
        // with out (bf16, bias already folded in).
        u64 hv[4][4];
#pragma unroll
        for (int m = 0; m < 4; ++m)
#pragma unroll
            for (int n = 0; n < 4; ++n)
                hv[m][n] = *(const u64*)(s_act + bX[m] + n * 4096);
        asm volatile("" ::: "memory");          // keep reads before writes
#pragma unroll
        for (int m = 0; m < 4; ++m)
#pragma unroll
            for (int n = 0; n < 4; ++n)
                *(u64*)(s_act + bX[m] + n * 4096) = pack4(out[m][n]);
#pragma unroll
        for (int m = 0; m < 4; ++m)
#pragma unroll
            for (int n = 0; n < 4; ++n) {
                f32x4 h;
                h[0] = bf2f((u16)(hv[m][n]      ));
                h[1] = bf2f((u16)(hv[m][n] >> 16));
                h[2] = bf2f((u16)(hv[m][n] >> 32));
                h[3] = bf2f((u16)(hv[m][n] >> 48));
                h_acc[m][n] = h;
            }
        __syncthreads();                        // out visible, Ws staged

        // --- paired GEMM2/3: sk += Ws.out ; h += Wr.out (B shared) --------
        // Aw from s_wst, Ar from s_wr (both LDS, conflict-free swizzle)
#pragma unroll
        for (int ks = 0; ks < 4; ++ks) {
            bf16x8 Aw[4], Ar[4];
#pragma unroll
            for (int m = 0; m < 4; ++m) {
                Aw[m] = *(const bf16x8*)(s_wst + bW[ks] + m * 4096);
                Ar[m] = *(const bf16x8*)(s_wr  + bW[ks] + m * 4096);
            }
#pragma unroll
            for (int n = 0; n < 4; ++n) {
                bf16x8 B = *(const bf16x8*)(s_act + bB[ks] + n * 4096);
#pragma unroll
                for (int m = 0; m < 4; ++m) {
                    sk[m][n]    = MFMA16(Aw[m], B, sk[m][n]);
                    h_acc[m][n] = MFMA16(Ar[m], B, h_acc[m][n]);
                }
            }
        }
        // per-layer biases: skip += bs, h += br
#pragma unroll
        for (int m = 0; m < 4; ++m) {
            f32x4 bsv = *(const f32x4*)(bs + l * 128 + wr * 64 + m * 16 + hi * 4);
            f32x4 brv = *(const f32x4*)(br + l * 128 + wr * 64 + m * 16 + hi * 4);
#pragma unroll
            for (int n = 0; n < 4; ++n) { sk[m][n] += bsv; h_acc[m][n] += brv; }
        }
        __syncthreads();                        // Ws, Wr & out reads done

        if (l < 9) {
            stage_w(wsb + (l + 1) * 16384, s_wst, woff, wid);   // Wd_{l+1}
            stage_w(wsb + (11 + l) * 16384, s_wr, woff, wid);   // Wr_{l+1}
            // write h (bf16) back to act
#pragma unroll
            for (int m = 0; m < 4; ++m)
#pragma unroll
                for (int n = 0; n < 4; ++n)
                    *(u64*)(s_act + bX[m] + n * 4096) = pack4(h_acc[m][n]);
            __syncthreads();                    // h visible, Wd+Wr ready
        }
    }

    // ---- final conv head --------------------------------------------------
    // act currently holds out_9 (reads all done). Write relu(skip) into act.
    stage_w(wsb + 30 * 16384, s_wst, woff, wid);       // Wf1
#pragma unroll
    for (int m = 0; m < 4; ++m)
#pragma unroll
        for (int n = 0; n < 4; ++n) {
            f32x4 v;
#pragma unroll
            for (int r = 0; r < 4; ++r) v[r] = fmaxf(sk[m][n][r], 0.f);
            *(u64*)(s_act + bX[m] + n * 4096) = pack4(v);
        }
    __syncthreads();

    // GEMM f1: g1 = relu(Wf1 . rs + bf1)
    f32x4 g1[4][4];
#pragma unroll
    for (int m = 0; m < 4; ++m) {
        f32x4 bv = *(const f32x4*)(bf1 + wr * 64 + m * 16 + hi * 4);
#pragma unroll
        for (int n = 0; n < 4; ++n) g1[m][n] = bv;
    }
#pragma unroll
    for (int ks = 0; ks < 4; ++ks) {
        bf16x8 A[4];
#pragma unroll
        for (int m = 0; m < 4; ++m) A[m] = *(const bf16x8*)(s_wst + bW[ks] + m * 4096);
#pragma unroll
        for (int n = 0; n < 4; ++n) {
            bf16x8 B = *(const bf16x8*)(s_act + bB[ks] + n * 4096);
#pragma unroll
            for (int m = 0; m < 4; ++m) g1[m][n] = MFMA16(A[m], B, g1[m][n]);
        }
    }
    __syncthreads();                            // reads done

    stage_w(wsb + 31 * 16384, s_wst, woff, wid);       // Wf2
#pragma unroll
    for (int m = 0; m < 4; ++m)
#pragma unroll
        for (int n = 0; n < 4; ++n) {
            f32x4 v;
#pragma unroll
            for (int r = 0; r < 4; ++r) v[r] = fmaxf(g1[m][n][r], 0.f);
            *(u64*)(s_act + bX[m] + n * 4096) = pack4(v);
        }
    __syncthreads();

    // GEMM f2: g2 = Wf2 . g1 + bf2
    f32x4 g2[4][4];
#pragma unroll
    for (int m = 0; m < 4; ++m) {
        f32x4 bv = *(const f32x4*)(bf2 + wr * 64 + m * 16 + hi * 4);
#pragma unroll
        for (int n = 0; n < 4; ++n) g2[m][n] = bv;
    }
#pragma unroll
    for (int ks = 0; ks < 4; ++ks) {
        bf16x8 A[4];
#pragma unroll
        for (int m = 0; m < 4; ++m) A[m] = *(const bf16x8*)(s_wst + bW[ks] + m * 4096);
#pragma unroll
        for (int n = 0; n < 4; ++n) {
            bf16x8 B = *(const bf16x8*)(s_act + bB[ks] + n * 4096);
#pragma unroll
            for (int m = 0; m < 4; ++m) g2[m][n] = MFMA16(A[m], B, g2[m][n]);
        }
    }

    // ---- column reduction: per-wave sums straight to global partials -----
    // partial layout: [blk][wc][128] floats
    f32x4 s[4];
#pragma unroll
    for (int m = 0; m < 4; ++m) {
        s[m] = g2[m][0];
#pragma unroll
        for (int n = 1; n < 4; ++n) s[m] += g2[m][n];
    }
#pragma unroll
    for (int m = 0; m < 4; ++m)
#pragma unroll
        for (int r = 0; r < 4; ++r) {
            float v = s[m][r];
            v += __shfl_xor(v, 1, 16);
            v += __shfl_xor(v, 2, 16);
            v += __shfl_xor(v, 4, 16);
            v += __shfl_xor(v, 8, 16);
            s[m][r] = v;
        }
    if (lo == 0) {
        float* pw = partial + ((size_t)(blk * 4 + wc)) * 128;
#pragma unroll
        for (int m = 0; m < 4; ++m)
#pragma unroll
            for (int r = 0; r < 4; ++r)
                pw[wr * 64 + m * 16 + hi * 4 + r] = s[m][r];
    }
}

// ---------------------------------------------------------------------------
// Deterministic final reduce:
// out[b][c] = (1/T) * sum_{tile 0..127, w 0..3} partial[((b*128+tile)*4+w)*128+c]
// Grid: 512 blocks (b*128+c) x 64 lanes.
// ---------------------------------------------------------------------------
__global__ void reduce_partials(const float* __restrict__ partial,
                                float* __restrict__ out) {
    int bc = blockIdx.x;             // 0..511
    int b  = bc >> 7, c = bc & 127;
    int lane = threadIdx.x;          // 0..63
    float s = 0.f;
#pragma unroll
    for (int i = 0; i < 2; ++i) {
        int tile = lane + 64 * i;
        int base = ((b * 128 + tile) * 4) * 128 + c;
        s += partial[base] + partial[base + 128] +
             partial[base + 256] + partial[base + 384];
    }
    s += __shfl_xor(s, 32);
    s += __shfl_xor(s, 16);
    s += __shfl_xor(s, 8);
    s += __shfl_xor(s, 4);
    s += __shfl_xor(s, 2);
    s += __shfl_xor(s, 1);
    if (lane == 0) out[b * 128 + c] = s * (1.0f / 32768.0f);
}

extern "C" void kernel_launch(void* const* d_in, const int* in_sizes, int n_in,
                              void* d_out, int out_size, void* d_ws, size_t ws_size,
                              hipStream_t stream) {
    const float* x   = (const float*)d_in[0];
    const float* Wd  = (const float*)d_in[1];
    const float* bd  = (const float*)d_in[2];
    const float* Wr  = (const float*)d_in[3];
    const float* br  = (const float*)d_in[4];
    const float* Ws  = (const float*)d_in[5];
    const float* bs  = (const float*)d_in[6];
    const float* Wf1 = (const float*)d_in[7];
    const float* bf1 = (const float*)d_in[8];
    const float* Wf2 = (const float*)d_in[9];
    const float* bf2 = (const float*)d_in[10];

    u16*   wsb     = (u16*)d_ws;                                  // 1 MB bf16 weights
    float* partial = (float*)((char*)d_ws + 32 * 16384 * 2);      // 1 MB partials

    convert_weights<<<2048, 256, 0, stream>>>(Wd, Wr, Ws, Wf1, Wf2, wsb);
    wavenet_main<<<512, 512, 0, stream>>>(x, wsb, bd, br, bs, bf1, bf2, partial);
    reduce_partials<<<512, 64, 0, stream>>>(partial, (float*)d_out);
}

// Round 11
// 187.667 us; speedup vs baseline: 2.9082x; 1.0042x over previous
//
#include <hip/hip_runtime.h>

// WaveNet fused kernel for MI355X (gfx950).
// L=10 layers of pointwise convs (C=128), B=4, T=32768.
// R11 = R10 + __launch_bounds__(512, 1): R10's single-arg bounds made the
// compiler cap at 128 VGPR and spill ~32 regs/thread (WRITE_SIZE 33MB vs 1MB
// of real output). arg2=1 raises the cap to ~256 (empirical law cap~=256/arg2);
// natural live set ~200 regs x 2 waves/SIMD = 400 <= 512 pool, so residency
// stays 2 waves/SIMD with zero spill. Everything else identical to R10.

typedef __bf16 bf16x8 __attribute__((ext_vector_type(8)));
typedef float  f32x4  __attribute__((ext_vector_type(4)));
typedef unsigned int uint;
typedef unsigned long long u64;
typedef unsigned short u16;

#define MFMA16(a, b, c) __builtin_amdgcn_mfma_f32_16x16x32_bf16((a), (b), (c), 0, 0, 0)

__device__ __forceinline__ u16 f2bf(float f) {
    uint u = __float_as_uint(f);
    u += 0x7fffu + ((u >> 16) & 1u);   // RNE
    return (u16)(u >> 16);
}
__device__ __forceinline__ float bf2f(u16 s) {
    return __uint_as_float(((uint)s) << 16);
}
__device__ __forceinline__ u64 pack4(f32x4 v) {
    uint a, b;
    asm("v_cvt_pk_bf16_f32 %0, %1, %2" : "=v"(a) : "v"(v[0]), "v"(v[1]));
    asm("v_cvt_pk_bf16_f32 %0, %1, %2" : "=v"(b) : "v"(v[2]), "v"(v[3]));
    return ((u64)b << 32) | (u64)a;
}

// ---------------------------------------------------------------------------
// Weight conversion: fp32 -> bf16 into d_ws, ALL slots pre-swizzled for the
// LDS image (linear global_load_lds copy yields conflict-free layout).
// Slot layout (16384 bf16): 0..9 Wd, 10..19 Wr, 20..29 Ws, 30 Wf1, 31 Wf2.
// ---------------------------------------------------------------------------
__global__ void convert_weights(const float* __restrict__ Wd,
                                const float* __restrict__ Wr,
                                const float* __restrict__ Ws,
                                const float* __restrict__ Wf1,
                                const float* __restrict__ Wf2,
                                u16* __restrict__ wsb) {
    int idx = blockIdx.x * 256 + threadIdx.x;
    if (idx >= 32 * 16384) return;
    int slot = idx >> 14;
    int a2   = idx & 16383;
    int r    = a2 >> 7;     // row (output channel)
    int c    = a2 & 127;    // bf16 column index within row
    const float* src;
    if (slot < 10)       { src = Wd  + slot * 16384; }
    else if (slot < 20)  { src = Wr  + (slot - 10) * 16384; }
    else if (slot < 30)  { src = Ws  + (slot - 20) * 16384; }
    else if (slot == 30) { src = Wf1; }
    else                 { src = Wf2; }
    int cs = c ^ ((r & 7) << 3);
    wsb[idx] = f2bf(src[r * 128 + cs]);
}

// ---------------------------------------------------------------------------
// Main fused kernel. Grid: 512 blocks (4 batches * 128 tiles), 512 threads
// (8 waves = 2 row-groups x 4 col-groups, each wave a 64x64 tile).
// LDS: s_act 64KB = Act[col 256][chan 128] bf16, byte ^= (col&7)<<4 swizzle
//      s_wst 32KB = staged Wd/Ws/Wf (pre-swizzled image, linear copy)
//      s_wr  32KB = staged Wr          -- total exactly 131072 B
// ---------------------------------------------------------------------------
__device__ __forceinline__ void stage_w(const u16* __restrict__ gsrc,
                                        unsigned char* lds, int woff, int wid) {
    // copy 32768 bytes linearly; 8 waves x 4 chunks of 1KB
#pragma unroll
    for (int i = 0; i < 4; ++i) {
        const u16* g = gsrc + woff + i * 512;
        __builtin_amdgcn_global_load_lds(
            (const __attribute__((address_space(1))) uint*)g,
            (__attribute__((address_space(3))) uint*)(lds + wid * 4096 + i * 1024),
            16, 0, 0);
    }
}

__global__ __launch_bounds__(512, 1)
void wavenet_main(const float* __restrict__ x,
                  const u16* __restrict__ wsb,
                  const float* __restrict__ bd,
                  const float* __restrict__ br,
                  const float* __restrict__ bs,
                  const float* __restrict__ bf1,
                  const float* __restrict__ bf2,
                  float* __restrict__ partial) {
    __shared__ __align__(16) unsigned char s_act[65536];
    __shared__ __align__(16) unsigned char s_wst[32768];
    __shared__ __align__(16) unsigned char s_wr[32768];

    const int tid  = threadIdx.x;
    const int lane = tid & 63;
    const int wid  = tid >> 6;      // 0..7
    const int wr   = wid >> 2;      // wave row (0..1): rows wr*64..+63
    const int wc   = wid & 3;       // wave col (0..3): cols wc*64..+63
    const int lo   = lane & 15;
    const int hi   = lane >> 4;

    // precomputed swizzled LDS base offsets (thread-constant):
    //   A-frag (weights):  s_wst/s_wr + bW[ks] + m*4096
    //   B-frag (act):      s_act + bB[ks] + n*4096
    //   exchange rows:     s_act + bX[m]  + n*4096   (hv read / out,h write)
    const int xc = (lo & 7) << 4;
    int bW[4], bB[4], bX[4];
#pragma unroll
    for (int ks = 0; ks < 4; ++ks) {
        int kk = ((ks << 6) + (hi << 4)) ^ xc;
        bW[ks] = (wr * 64 + lo) * 256 + kk;
        bB[ks] = (wc * 64 + lo) * 256 + kk;
    }
#pragma unroll
    for (int m = 0; m < 4; ++m)
        bX[m] = (wc * 64 + lo) * 256 + ((wr * 128 + m * 32 + hi * 8) ^ xc);

    const int woff = wid * 2048 + lane * 8;   // stage_w per-thread src offset

    const int blk = blockIdx.x;
    const int b   = blk >> 7;               // 128 tiles per batch
    const int t0  = (blk & 127) * 256;

    // ---- issue stage of Wd_0 + Wr_0 (async), then stage x tile into s_act --
    stage_w(wsb + 0 * 16384, s_wst, woff, wid);
    stage_w(wsb + 10 * 16384, s_wr, woff, wid);

    {
        const float* xb = x + (size_t)b * (128u * 32768u) + t0;
#pragma unroll
        for (int i = 0; i < 16; ++i) {
            int task = wid * 16 + i;        // 128 tasks: 32 chan-groups x 4 t-chunks
            int tc = task & 3;
            int cg = task >> 2;
            int t  = tc * 64 + lane;        // col in tile (0..255)
            int c0 = cg * 4;
            f32x4 v;
            v[0] = xb[(c0 + 0) * 32768 + t];
            v[1] = xb[(c0 + 1) * 32768 + t];
            v[2] = xb[(c0 + 2) * 32768 + t];
            v[3] = xb[(c0 + 3) * 32768 + t];
            int byte = t * 256 + ((c0 * 2) ^ ((t & 7) << 4));
            *(u64*)(s_act + byte) = pack4(v);
        }
    }

    // skip accumulator (fp32, persistent across layers)
    f32x4 sk[4][4];
#pragma unroll
    for (int m = 0; m < 4; ++m)
#pragma unroll
        for (int n = 0; n < 4; ++n) { f32x4 z = {0.f, 0.f, 0.f, 0.f}; sk[m][n] = z; }

    __syncthreads();    // x staged, Wd0+Wr0 ready (barrier drains vmcnt+lgkmcnt)

    f32x4 h_acc[4][4];

#pragma unroll 1
    for (int l = 0; l < 10; ++l) {
        // --- GEMM1: out = Wd . h + bd  (A = s_wst, B = s_act) -------------
        f32x4 bdv[4];
#pragma unroll
        for (int m = 0; m < 4; ++m)
            bdv[m] = *(const f32x4*)(bd + l * 128 + wr * 64 + m * 16 + hi * 4);

        f32x4 out[4][4];
#pragma unroll
        for (int m = 0; m < 4; ++m)
#pragma unroll
            for (int n = 0; n < 4; ++n) out[m][n] = bdv[m];

#pragma unroll
        for (int ks = 0; ks < 4; ++ks) {
            bf16x8 A[4];
#pragma unroll
            for (int m = 0; m < 4; ++m) A[m] = *(const bf16x8*)(s_wst + bW[ks] + m * 4096);
#pragma unroll
            for (int n = 0; n < 4; ++n) {
                bf16x8 B = *(const bf16x8*)(s_act + bB[ks] + n * 4096);
#pragma unroll
                for (int m = 0; m < 4; ++m) out[m][n] = MFMA16(A[m], B, out[m][n]);
            }
        }
        __syncthreads();                        // all reads of h & Wd done

        // issue stage of Ws_l over Wd (reads completed at barrier)
        stage_w(wsb + (20 + l) * 16384, s_wst, woff, wid);

        // read h (C-init for residual GEMM) from own region, then overwrite
        // with out (bf16, bias already folded in).
        u64 hv[4][4];
#pragma unroll
        for (int m = 0; m < 4; ++m)
#pragma unroll
            for (int n = 0; n < 4; ++n)
                hv[m][n] = *(const u64*)(s_act + bX[m] + n * 4096);
        asm volatile("" ::: "memory");          // keep reads before writes
#pragma unroll
        for (int m = 0; m < 4; ++m)
#pragma unroll
            for (int n = 0; n < 4; ++n)
                *(u64*)(s_act + bX[m] + n * 4096) = pack4(out[m][n]);
#pragma unroll
        for (int m = 0; m < 4; ++m)
#pragma unroll
            for (int n = 0; n < 4; ++n) {
                f32x4 h;
                h[0] = bf2f((u16)(hv[m][n]      ));
                h[1] = bf2f((u16)(hv[m][n] >> 16));
                h[2] = bf2f((u16)(hv[m][n] >> 32));
                h[3] = bf2f((u16)(hv[m][n] >> 48));
                h_acc[m][n] = h;
            }
        __syncthreads();                        // out visible, Ws staged

        // --- paired GEMM2/3: sk += Ws.out ; h += Wr.out (B shared) --------
        // Aw from s_wst, Ar from s_wr (both LDS, conflict-free swizzle)
#pragma unroll
        for (int ks = 0; ks < 4; ++ks) {
            bf16x8 Aw[4], Ar[4];
#pragma unroll
            for (int m = 0; m < 4; ++m) {
                Aw[m] = *(const bf16x8*)(s_wst + bW[ks] + m * 4096);
                Ar[m] = *(const bf16x8*)(s_wr  + bW[ks] + m * 4096);
            }
#pragma unroll
            for (int n = 0; n < 4; ++n) {
                bf16x8 B = *(const bf16x8*)(s_act + bB[ks] + n * 4096);
#pragma unroll
                for (int m = 0; m < 4; ++m) {
                    sk[m][n]    = MFMA16(Aw[m], B, sk[m][n]);
                    h_acc[m][n] = MFMA16(Ar[m], B, h_acc[m][n]);
                }
            }
        }
        // per-layer biases: skip += bs, h += br
#pragma unroll
        for (int m = 0; m < 4; ++m) {
            f32x4 bsv = *(const f32x4*)(bs + l * 128 + wr * 64 + m * 16 + hi * 4);
            f32x4 brv = *(const f32x4*)(br + l * 128 + wr * 64 + m * 16 + hi * 4);
#pragma unroll
            for (int n = 0; n < 4; ++n) { sk[m][n] += bsv; h_acc[m][n] += brv; }
        }
        __syncthreads();                        // Ws, Wr & out reads done

        if (l < 9) {
            stage_w(wsb + (l + 1) * 16384, s_wst, woff, wid);   // Wd_{l+1}
            stage_w(wsb + (11 + l) * 16384, s_wr, woff, wid);   // Wr_{l+1}
            // write h (bf16) back to act
#pragma unroll
            for (int m = 0; m < 4; ++m)
#pragma unroll
                for (int n = 0; n < 4; ++n)
                    *(u64*)(s_act + bX[m] + n * 4096) = pack4(h_acc[m][n]);
            __syncthreads();                    // h visible, Wd+Wr ready
        }
    }

    // ---- final conv head --------------------------------------------------
    // act currently holds out_9 (reads all done). Write relu(skip) into act.
    stage_w(wsb + 30 * 16384, s_wst, woff, wid);       // Wf1
#pragma unroll
    for (int m = 0; m < 4; ++m)
#pragma unroll
        for (int n = 0; n < 4; ++n) {
            f32x4 v;
#pragma unroll
            for (int r = 0; r < 4; ++r) v[r] = fmaxf(sk[m][n][r], 0.f);
            *(u64*)(s_act + bX[m] + n * 4096) = pack4(v);
        }
    __syncthreads();

    // GEMM f1: g1 = relu(Wf1 . rs + bf1)
    f32x4 g1[4][4];
#pragma unroll
    for (int m = 0; m < 4; ++m) {
        f32x4 bv = *(const f32x4*)(bf1 + wr * 64 + m * 16 + hi * 4);
#pragma unroll
        for (int n = 0; n < 4; ++n) g1[m][n] = bv;
    }
#pragma unroll
    for (int ks = 0; ks < 4; ++ks) {
        bf16x8 A[4];
#pragma unroll
        for (int m = 0; m < 4; ++m) A[m] = *(const bf16x8*)(s_wst + bW[ks] + m * 4096);
#pragma unroll
        for (int n = 0; n < 4; ++n) {
            bf16x8 B = *(const bf16x8*)(s_act + bB[ks] + n * 4096);
#pragma unroll
            for (int m = 0; m < 4; ++m) g1[m][n] = MFMA16(A[m], B, g1[m][n]);
        }
    }
    __syncthreads();                            // reads done

    stage_w(wsb + 31 * 16384, s_wst, woff, wid);       // Wf2
#pragma unroll
    for (int m = 0; m < 4; ++m)
#pragma unroll
        for (int n = 0; n < 4; ++n) {
            f32x4 v;
#pragma unroll
            for (int r = 0; r < 4; ++r) v[r] = fmaxf(g1[m][n][r], 0.f);
            *(u64*)(s_act + bX[m] + n * 4096) = pack4(v);
        }
    __syncthreads();

    // GEMM f2: g2 = Wf2 . g1 + bf2
    f32x4 g2[4][4];
#pragma unroll
    for (int m = 0; m < 4; ++m) {
        f32x4 bv = *(const f32x4*)(bf2 + wr * 64 + m * 16 + hi * 4);
#pragma unroll
        for (int n = 0; n < 4; ++n) g2[m][n] = bv;
    }
#pragma unroll
    for (int ks = 0; ks < 4; ++ks) {
        bf16x8 A[4];
#pragma unroll
        for (int m = 0; m < 4; ++m) A[m] = *(const bf16x8*)(s_wst + bW[ks] + m * 4096);
#pragma unroll
        for (int n = 0; n < 4; ++n) {
            bf16x8 B = *(const bf16x8*)(s_act + bB[ks] + n * 4096);
#pragma unroll
            for (int m = 0; m < 4; ++m) g2[m][n] = MFMA16(A[m], B, g2[m][n]);
        }
    }

    // ---- column reduction: per-wave sums straight to global partials -----
    // partial layout: [blk][wc][128] floats
    f32x4 s[4];
#pragma unroll
    for (int m = 0; m < 4; ++m) {
        s[m] = g2[m][0];
#pragma unroll
        for (int n = 1; n < 4; ++n) s[m] += g2[m][n];
    }
#pragma unroll
    for (int m = 0; m < 4; ++m)
#pragma unroll
        for (int r = 0; r < 4; ++r) {
            float v = s[m][r];
            v += __shfl_xor(v, 1, 16);
            v += __shfl_xor(v, 2, 16);
            v += __shfl_xor(v, 4, 16);
            v += __shfl_xor(v, 8, 16);
            s[m][r] = v;
        }
    if (lo == 0) {
        float* pw = partial + ((size_t)(blk * 4 + wc)) * 128;
#pragma unroll
        for (int m = 0; m < 4; ++m)
#pragma unroll
            for (int r = 0; r < 4; ++r)
                pw[wr * 64 + m * 16 + hi * 4 + r] = s[m][r];
    }
}

// ---------------------------------------------------------------------------
// Deterministic final reduce:
// out[b][c] = (1/T) * sum_{tile 0..127, w 0..3} partial[((b*128+tile)*4+w)*128+c]
// Grid: 512 blocks (b*128+c) x 64 lanes.
// ---------------------------------------------------------------------------
__global__ void reduce_partials(const float* __restrict__ partial,
                                float* __restrict__ out) {
    int bc = blockIdx.x;             // 0..511
    int b  = bc >> 7, c = bc & 127;
    int lane = threadIdx.x;          // 0..63
    float s = 0.f;
#pragma unroll
    for (int i = 0; i < 2; ++i) {
        int tile = lane + 64 * i;
        int base = ((b * 128 + tile) * 4) * 128 + c;
        s += partial[base] + partial[base + 128] +
             partial[base + 256] + partial[base + 384];
    }
    s += __shfl_xor(s, 32);
    s += __shfl_xor(s, 16);
    s += __shfl_xor(s, 8);
    s += __shfl_xor(s, 4);
    s += __shfl_xor(s, 2);
    s += __shfl_xor(s, 1);
    if (lane == 0) out[b * 128 + c] = s * (1.0f / 32768.0f);
}

extern "C" void kernel_launch(void* const* d_in, const int* in_sizes, int n_in,
                              void* d_out, int out_size, void* d_ws, size_t ws_size,
                              hipStream_t stream) {
    const float* x   = (const float*)d_in[0];
    const float* Wd  = (const float*)d_in[1];
    const float* bd  = (const float*)d_in[2];
    const float* Wr  = (const float*)d_in[3];
    const float* br  = (const float*)d_in[4];
    const float* Ws  = (const float*)d_in[5];
    const float* bs  = (const float*)d_in[6];
    const float* Wf1 = (const float*)d_in[7];
    const float* bf1 = (const float*)d_in[8];
    const float* Wf2 = (const float*)d_in[9];
    const float* bf2 = (const float*)d_in[10];

    u16*   wsb     = (u16*)d_ws;                                  // 1 MB bf16 weights
    float* partial = (float*)((char*)d_ws + 32 * 16384 * 2);      // 1 MB partials

    convert_weights<<<2048, 256, 0, stream>>>(Wd, Wr, Ws, Wf1, Wf2, wsb);
    wavenet_main<<<512, 512, 0, stream>>>(x, wsb, bd, br, bs, bf1, bf2, partial);
    reduce_partials<<<512, 64, 0, stream>>>(partial, (float*)d_out);
}

// Round 14
// 167.054 us; speedup vs baseline: 3.2670x; 1.1234x over previous
//
#include <hip/hip_runtime.h>

// WaveNet fused kernel for MI355X (gfx950).
// L=10 layers of pointwise convs (C=128), B=4, T=32768.
// R14 = R11 EXACT (known-good 188us: 8-wave 128x256 block, 64x64 wave tiles,
// Wd/Ws + Wr LDS-staged, hv-bridged h exchange, LDS=131072B, (512,1))
// + ONE arch-reg trim: GEMM2/3 loads B[4] once per ks and Aw/Ar per-m
// (peak fragment temps 36->24 regs) to shrink the ~33MB arch-spill.
// Register law learned (R7/R9/R13 infs): acc arrays live at once must stay
// <=128 regs (two [4][4] f32x4 max) and LDS <=128KiB, else silent launch fail.

typedef __bf16 bf16x8 __attribute__((ext_vector_type(8)));
typedef float  f32x4  __attribute__((ext_vector_type(4)));
typedef unsigned int uint;
typedef unsigned long long u64;
typedef unsigned short u16;

#define MFMA16(a, b, c) __builtin_amdgcn_mfma_f32_16x16x32_bf16((a), (b), (c), 0, 0, 0)

__device__ __forceinline__ u16 f2bf(float f) {
    uint u = __float_as_uint(f);
    u += 0x7fffu + ((u >> 16) & 1u);   // RNE
    return (u16)(u >> 16);
}
__device__ __forceinline__ float bf2f(u16 s) {
    return __uint_as_float(((uint)s) << 16);
}
__device__ __forceinline__ u64 pack4(f32x4 v) {
    uint a, b;
    asm("v_cvt_pk_bf16_f32 %0, %1, %2" : "=v"(a) : "v"(v[0]), "v"(v[1]));
    asm("v_cvt_pk_bf16_f32 %0, %1, %2" : "=v"(b) : "v"(v[2]), "v"(v[3]));
    return ((u64)b << 32) | (u64)a;
}

// ---------------------------------------------------------------------------
// Weight conversion: fp32 -> bf16 into d_ws, ALL slots pre-swizzled for the
// LDS image (linear global_load_lds copy yields conflict-free layout).
// Slot layout (16384 bf16): 0..9 Wd, 10..19 Wr, 20..29 Ws, 30 Wf1, 31 Wf2.
// ---------------------------------------------------------------------------
__global__ void convert_weights(const float* __restrict__ Wd,
                                const float* __restrict__ Wr,
                                const float* __restrict__ Ws,
                                const float* __restrict__ Wf1,
                                const float* __restrict__ Wf2,
                                u16* __restrict__ wsb) {
    int idx = blockIdx.x * 256 + threadIdx.x;
    if (idx >= 32 * 16384) return;
    int slot = idx >> 14;
    int a2   = idx & 16383;
    int r    = a2 >> 7;     // row (output channel)
    int c    = a2 & 127;    // bf16 column index within row
    const float* src;
    if (slot < 10)       { src = Wd  + slot * 16384; }
    else if (slot < 20)  { src = Wr  + (slot - 10) * 16384; }
    else if (slot < 30)  { src = Ws  + (slot - 20) * 16384; }
    else if (slot == 30) { src = Wf1; }
    else                 { src = Wf2; }
    int cs = c ^ ((r & 7) << 3);
    wsb[idx] = f2bf(src[r * 128 + cs]);
}

// ---------------------------------------------------------------------------
// Main fused kernel. Grid: 512 blocks (4 batches * 128 tiles), 512 threads
// (8 waves = 2 row-groups x 4 col-groups, each wave a 64x64 tile).
// LDS: s_act 64KB = Act[col 256][chan 128] bf16, byte ^= (col&7)<<4 swizzle
//      s_wst 32KB = staged Wd/Ws/Wf (pre-swizzled image, linear copy)
//      s_wr  32KB = staged Wr          -- total exactly 131072 B
// ---------------------------------------------------------------------------
__device__ __forceinline__ void stage_w(const u16* __restrict__ gsrc,
                                        unsigned char* lds, int woff, int wid) {
    // copy 32768 bytes linearly; 8 waves x 4 chunks of 1KB
#pragma unroll
    for (int i = 0; i < 4; ++i) {
        const u16* g = gsrc + woff + i * 512;
        __builtin_amdgcn_global_load_lds(
            (const __attribute__((address_space(1))) uint*)g,
            (__attribute__((address_space(3))) uint*)(lds + wid * 4096 + i * 1024),
            16, 0, 0);
    }
}

__global__ __launch_bounds__(512, 1)
void wavenet_main(const float* __restrict__ x,
                  const u16* __restrict__ wsb,
                  const float* __restrict__ bd,
                  const float* __restrict__ br,
                  const float* __restrict__ bs,
                  const float* __restrict__ bf1,
                  const float* __restrict__ bf2,
                  float* __restrict__ partial) {
    __shared__ __align__(16) unsigned char s_act[65536];
    __shared__ __align__(16) unsigned char s_wst[32768];
    __shared__ __align__(16) unsigned char s_wr[32768];

    const int tid  = threadIdx.x;
    const int lane = tid & 63;
    const int wid  = tid >> 6;      // 0..7
    const int wr   = wid >> 2;      // wave row (0..1): rows wr*64..+63
    const int wc   = wid & 3;       // wave col (0..3): cols wc*64..+63
    const int lo   = lane & 15;
    const int hi   = lane >> 4;

    // precomputed swizzled LDS base offsets (thread-constant):
    //   A-frag (weights):  s_wst/s_wr + bW[ks] + m*4096
    //   B-frag (act):      s_act + bB[ks] + n*4096
    //   exchange rows:     s_act + bX[m]  + n*4096   (hv read / out,h write)
    const int xc = (lo & 7) << 4;
    int bW[4], bB[4], bX[4];
#pragma unroll
    for (int ks = 0; ks < 4; ++ks) {
        int kk = ((ks << 6) + (hi << 4)) ^ xc;
        bW[ks] = (wr * 64 + lo) * 256 + kk;
        bB[ks] = (wc * 64 + lo) * 256 + kk;
    }
#pragma unroll
    for (int m = 0; m < 4; ++m)
        bX[m] = (wc * 64 + lo) * 256 + ((wr * 128 + m * 32 + hi * 8) ^ xc);

    const int woff = wid * 2048 + lane * 8;   // stage_w per-thread src offset

    const int blk = blockIdx.x;
    const int b   = blk >> 7;               // 128 tiles per batch
    const int t0  = (blk & 127) * 256;

    // ---- issue stage of Wd_0 + Wr_0 (async), then stage x tile into s_act --
    stage_w(wsb + 0 * 16384, s_wst, woff, wid);
    stage_w(wsb + 10 * 16384, s_wr, woff, wid);

    {
        const float* xb = x + (size_t)b * (128u * 32768u) + t0;
#pragma unroll
        for (int i = 0; i < 16; ++i) {
            int task = wid * 16 + i;        // 128 tasks: 32 chan-groups x 4 t-chunks
            int tc = task & 3;
            int cg = task >> 2;
            int t  = tc * 64 + lane;        // col in tile (0..255)
            int c0 = cg * 4;
            f32x4 v;
            v[0] = xb[(c0 + 0) * 32768 + t];
            v[1] = xb[(c0 + 1) * 32768 + t];
            v[2] = xb[(c0 + 2) * 32768 + t];
            v[3] = xb[(c0 + 3) * 32768 + t];
            int byte = t * 256 + ((c0 * 2) ^ ((t & 7) << 4));
            *(u64*)(s_act + byte) = pack4(v);
        }
    }

    // skip accumulator (fp32, persistent across layers)
    f32x4 sk[4][4];
#pragma unroll
    for (int m = 0; m < 4; ++m)
#pragma unroll
        for (int n = 0; n < 4; ++n) { f32x4 z = {0.f, 0.f, 0.f, 0.f}; sk[m][n] = z; }

    __syncthreads();    // x staged, Wd0+Wr0 ready (barrier drains vmcnt+lgkmcnt)

    f32x4 h_acc[4][4];

#pragma unroll 1
    for (int l = 0; l < 10; ++l) {
        // --- GEMM1: out = Wd . h + bd  (A = s_wst, B = s_act) -------------
        f32x4 bdv[4];
#pragma unroll
        for (int m = 0; m < 4; ++m)
            bdv[m] = *(const f32x4*)(bd + l * 128 + wr * 64 + m * 16 + hi * 4);

        f32x4 out[4][4];
#pragma unroll
        for (int m = 0; m < 4; ++m)
#pragma unroll
            for (int n = 0; n < 4; ++n) out[m][n] = bdv[m];

#pragma unroll
        for (int ks = 0; ks < 4; ++ks) {
            bf16x8 A[4];
#pragma unroll
            for (int m = 0; m < 4; ++m) A[m] = *(const bf16x8*)(s_wst + bW[ks] + m * 4096);
#pragma unroll
            for (int n = 0; n < 4; ++n) {
                bf16x8 B = *(const bf16x8*)(s_act + bB[ks] + n * 4096);
#pragma unroll
                for (int m = 0; m < 4; ++m) out[m][n] = MFMA16(A[m], B, out[m][n]);
            }
        }
        __syncthreads();                        // all reads of h & Wd done

        // issue stage of Ws_l over Wd (reads completed at barrier)
        stage_w(wsb + (20 + l) * 16384, s_wst, woff, wid);

        // read h (C-init for residual GEMM) from own region, then overwrite
        // with out (bf16, bias already folded in).  [R11 known-good form]
        u64 hv[4][4];
#pragma unroll
        for (int m = 0; m < 4; ++m)
#pragma unroll
            for (int n = 0; n < 4; ++n)
                hv[m][n] = *(const u64*)(s_act + bX[m] + n * 4096);
        asm volatile("" ::: "memory");          // keep reads before writes
#pragma unroll
        for (int m = 0; m < 4; ++m)
#pragma unroll
            for (int n = 0; n < 4; ++n)
                *(u64*)(s_act + bX[m] + n * 4096) = pack4(out[m][n]);
#pragma unroll
        for (int m = 0; m < 4; ++m)
#pragma unroll
            for (int n = 0; n < 4; ++n) {
                f32x4 h;
                h[0] = bf2f((u16)(hv[m][n]      ));
                h[1] = bf2f((u16)(hv[m][n] >> 16));
                h[2] = bf2f((u16)(hv[m][n] >> 32));
                h[3] = bf2f((u16)(hv[m][n] >> 48));
                h_acc[m][n] = h;
            }
        __syncthreads();                        // out visible, Ws staged

        // --- paired GEMM2/3: sk += Ws.out ; h_acc += Wr.out (B shared) ----
        // Arch-reg trim: B[4] loaded once per ks, Aw/Ar per-m (temps 36->24).
#pragma unroll
        for (int ks = 0; ks < 4; ++ks) {
            bf16x8 B[4];
#pragma unroll
            for (int n = 0; n < 4; ++n) B[n] = *(const bf16x8*)(s_act + bB[ks] + n * 4096);
#pragma unroll
            for (int m = 0; m < 4; ++m) {
                bf16x8 Aw = *(const bf16x8*)(s_wst + bW[ks] + m * 4096);
                bf16x8 Ar = *(const bf16x8*)(s_wr  + bW[ks] + m * 4096);
#pragma unroll
                for (int n = 0; n < 4; ++n) {
                    sk[m][n]    = MFMA16(Aw, B[n], sk[m][n]);
                    h_acc[m][n] = MFMA16(Ar, B[n], h_acc[m][n]);
                }
            }
        }
        // per-layer biases: skip += bs, h += br
#pragma unroll
        for (int m = 0; m < 4; ++m) {
            f32x4 bsv = *(const f32x4*)(bs + l * 128 + wr * 64 + m * 16 + hi * 4);
            f32x4 brv = *(const f32x4*)(br + l * 128 + wr * 64 + m * 16 + hi * 4);
#pragma unroll
            for (int n = 0; n < 4; ++n) { sk[m][n] += bsv; h_acc[m][n] += brv; }
        }
        __syncthreads();                        // Ws, Wr & out reads done

        if (l < 9) {
            stage_w(wsb + (l + 1) * 16384, s_wst, woff, wid);   // Wd_{l+1}
            stage_w(wsb + (11 + l) * 16384, s_wr, woff, wid);   // Wr_{l+1}
            // write h (bf16) back to act
#pragma unroll
            for (int m = 0; m < 4; ++m)
#pragma unroll
                for (int n = 0; n < 4; ++n)
                    *(u64*)(s_act + bX[m] + n * 4096) = pack4(h_acc[m][n]);
            __syncthreads();                    // h visible, Wd+Wr ready
        }
    }

    // ---- final conv head --------------------------------------------------
    // act currently holds out_9 (reads all done). Write relu(skip) into act.
    stage_w(wsb + 30 * 16384, s_wst, woff, wid);       // Wf1
#pragma unroll
    for (int m = 0; m < 4; ++m)
#pragma unroll
        for (int n = 0; n < 4; ++n) {
            f32x4 v;
#pragma unroll
            for (int r = 0; r < 4; ++r) v[r] = fmaxf(sk[m][n][r], 0.f);
            *(u64*)(s_act + bX[m] + n * 4096) = pack4(v);
        }
    __syncthreads();

    // GEMM f1: g1 = relu(Wf1 . rs + bf1)
    f32x4 g1[4][4];
#pragma unroll
    for (int m = 0; m < 4; ++m) {
        f32x4 bv = *(const f32x4*)(bf1 + wr * 64 + m * 16 + hi * 4);
#pragma unroll
        for (int n = 0; n < 4; ++n) g1[m][n] = bv;
    }
#pragma unroll
    for (int ks = 0; ks < 4; ++ks) {
        bf16x8 A[4];
#pragma unroll
        for (int m = 0; m < 4; ++m) A[m] = *(const bf16x8*)(s_wst + bW[ks] + m * 4096);
#pragma unroll
        for (int n = 0; n < 4; ++n) {
            bf16x8 B = *(const bf16x8*)(s_act + bB[ks] + n * 4096);
#pragma unroll
            for (int m = 0; m < 4; ++m) g1[m][n] = MFMA16(A[m], B, g1[m][n]);
        }
    }
    __syncthreads();                            // reads done

    stage_w(wsb + 31 * 16384, s_wst, woff, wid);       // Wf2
#pragma unroll
    for (int m = 0; m < 4; ++m)
#pragma unroll
        for (int n = 0; n < 4; ++n) {
            f32x4 v;
#pragma unroll
            for (int r = 0; r < 4; ++r) v[r] = fmaxf(g1[m][n][r], 0.f);
            *(u64*)(s_act + bX[m] + n * 4096) = pack4(v);
        }
    __syncthreads();

    // GEMM f2: g2 = Wf2 . g1 + bf2
    f32x4 g2[4][4];
#pragma unroll
    for (int m = 0; m < 4; ++m) {
        f32x4 bv = *(const f32x4*)(bf2 + wr * 64 + m * 16 + hi * 4);
#pragma unroll
        for (int n = 0; n < 4; ++n) g2[m][n] = bv;
    }
#pragma unroll
    for (int ks = 0; ks < 4; ++ks) {
        bf16x8 A[4];
#pragma unroll
        for (int m = 0; m < 4; ++m) A[m] = *(const bf16x8*)(s_wst + bW[ks] + m * 4096);
#pragma unroll
        for (int n = 0; n < 4; ++n) {
            bf16x8 B = *(const bf16x8*)(s_act + bB[ks] + n * 4096);
#pragma unroll
            for (int m = 0; m < 4; ++m) g2[m][n] = MFMA16(A[m], B, g2[m][n]);
        }
    }

    // ---- column reduction: per-wave sums straight to global partials -----
    // partial layout: [blk][wc][128] floats
    f32x4 s[4];
#pragma unroll
    for (int m = 0; m < 4; ++m) {
        s[m] = g2[m][0];
#pragma unroll
        for (int n = 1; n < 4; ++n) s[m] += g2[m][n];
    }
#pragma unroll
    for (int m = 0; m < 4; ++m)
#pragma unroll
        for (int r = 0; r < 4; ++r) {
            float v = s[m][r];
            v += __shfl_xor(v, 1, 16);
            v += __shfl_xor(v, 2, 16);
            v += __shfl_xor(v, 4, 16);
            v += __shfl_xor(v, 8, 16);
            s[m][r] = v;
        }
    if (lo == 0) {
        float* pw = partial + ((size_t)(blk * 4 + wc)) * 128;
#pragma unroll
        for (int m = 0; m < 4; ++m)
#pragma unroll
            for (int r = 0; r < 4; ++r)
                pw[wr * 64 + m * 16 + hi * 4 + r] = s[m][r];
    }
}

// ---------------------------------------------------------------------------
// Deterministic final reduce:
// out[b][c] = (1/T) * sum_{tile 0..127, w 0..3} partial[((b*128+tile)*4+w)*128+c]
// Grid: 512 blocks (b*128+c) x 64 lanes.
// ---------------------------------------------------------------------------
__global__ void reduce_partials(const float* __restrict__ partial,
                                float* __restrict__ out) {
    int bc = blockIdx.x;             // 0..511
    int b  = bc >> 7, c = bc & 127;
    int lane = threadIdx.x;          // 0..63
    float s = 0.f;
#pragma unroll
    for (int i = 0; i < 2; ++i) {
        int tile = lane + 64 * i;
        int base = ((b * 128 + tile) * 4) * 128 + c;
        s += partial[base] + partial[base + 128] +
             partial[base + 256] + partial[base + 384];
    }
    s += __shfl_xor(s, 32);
    s += __shfl_xor(s, 16);
    s += __shfl_xor(s, 8);
    s += __shfl_xor(s, 4);
    s += __shfl_xor(s, 2);
    s += __shfl_xor(s, 1);
    if (lane == 0) out[b * 128 + c] = s * (1.0f / 32768.0f);
}

extern "C" void kernel_launch(void* const* d_in, const int* in_sizes, int n_in,
                              void* d_out, int out_size, void* d_ws, size_t ws_size,
                              hipStream_t stream) {
    const float* x   = (const float*)d_in[0];
    const float* Wd  = (const float*)d_in[1];
    const float* bd  = (const float*)d_in[2];
    const float* Wr  = (const float*)d_in[3];
    const float* br  = (const float*)d_in[4];
    const float* Ws  = (const float*)d_in[5];
    const float* bs  = (const float*)d_in[6];
    const float* Wf1 = (const float*)d_in[7];
    const float* bf1 = (const float*)d_in[8];
    const float* Wf2 = (const float*)d_in[9];
    const float* bf2 = (const float*)d_in[10];

    u16*   wsb     = (u16*)d_ws;                                  // 1 MB bf16 weights
    float* partial = (float*)((char*)d_ws + 32 * 16384 * 2);      // 1 MB partials

    convert_weights<<<2048, 256, 0, stream>>>(Wd, Wr, Ws, Wf1, Wf2, wsb);
    wavenet_main<<<512, 512, 0, stream>>>(x, wsb, bd, br, bs, bf1, bf2, partial);
    reduce_partials<<<512, 64, 0, stream>>>(partial, (float*)d_out);
}